// Round 2
// baseline (4900.509 us; speedup 1.0000x reference)
//
#include <hip/hip_runtime.h>
#include <hip/hip_bf16.h>
#include <cstdint>

// ---------------------------------------------------------------------------
// HeteroGNN: 2-layer hetero-SAGE (7 rel, 1.6M edges) + classifier, 100k nodes.
// Design C (low-memory, ~260 MB workspace):
//  * CSR build per call (deg histogram -> scan -> counting-sort scatter),
//    reused by both layers (edges identical).
//  * Per relation r: gather_mean (raw bf16 rows, CSR, no atomics) -> GEMM
//    accumulating hacc += (1/7) * mean_r @ Wneigh[r]  (fp32 RMW, L3-resident).
//  * Self term: one GEMM per layer with pre-summed sum_r Wself[r].
//  * bf16 MFMA 16x16x32, 128x128 tiles, fp32 accumulate.
//  * Aliasing: mean2/h2b over [x|mean1]; z1 over hacc.
// ---------------------------------------------------------------------------

#define NN 100000
#define NREL 7
#define NE 1600000

using uint = unsigned int;
using ushort_t = unsigned short;
using bf16x8 = __attribute__((ext_vector_type(8))) __bf16;
using f32x4 = __attribute__((ext_vector_type(4))) float;

__device__ __forceinline__ ushort_t f32_to_bf16(float f) {
    uint u = __float_as_uint(f);
    u += 0x7fffu + ((u >> 16) & 1u);
    return (ushort_t)(u >> 16);
}
__device__ __forceinline__ float bf16lo(uint u) { return __uint_as_float(u << 16); }
__device__ __forceinline__ float bf16hi(uint u) { return __uint_as_float(u & 0xffff0000u); }

// ---------------- CSR build ----------------
__global__ void deg_k(const int* __restrict__ edges, int* __restrict__ deg) {
    int r = blockIdx.y;
    int e = blockIdx.x * 256 + threadIdx.x;
    int d = edges[(size_t)(2 * r + 1) * NE + e];
    atomicAdd(&deg[r * NN + d], 1);
}

__global__ void scan1_k(const int* __restrict__ deg, int* __restrict__ rowptr,
                        int* __restrict__ blk, int total) {
    __shared__ int wsum[4];
    int t = threadIdx.x;
    int base = blockIdx.x * 4096 + t * 16;
    int vals[16];
    int s = 0;
#pragma unroll
    for (int i = 0; i < 16; ++i) {
        int g = base + i;
        int v = (g < total) ? deg[g] : 0;
        vals[i] = s;
        s += v;
    }
    int lane = t & 63, w = t >> 6;
    int x = s;
    for (int off = 1; off < 64; off <<= 1) {
        int y = __shfl_up(x, off);
        if (lane >= off) x += y;
    }
    if (lane == 63) wsum[w] = x;
    __syncthreads();
    if (t == 0) {
        int a = 0;
#pragma unroll
        for (int k = 0; k < 4; ++k) { int b = wsum[k]; wsum[k] = a; a += b; }
        blk[blockIdx.x] = a;
    }
    __syncthreads();
    int excl = x - s + wsum[w];
#pragma unroll
    for (int i = 0; i < 16; ++i) {
        int g = base + i;
        if (g < total) rowptr[g] = excl + vals[i];
    }
}

__global__ void scan2_k(int* blk, int nb) {
    if (threadIdx.x == 0 && blockIdx.x == 0) {
        int a = 0;
        for (int i = 0; i < nb; ++i) { int b = blk[i]; blk[i] = a; a += b; }
    }
}

__global__ void scan3_k(int* __restrict__ rowptr, const int* __restrict__ blk, int total) {
    int t = threadIdx.x;
    int add = blk[blockIdx.x];
    int base = blockIdx.x * 4096 + t * 16;
#pragma unroll
    for (int i = 0; i < 16; ++i) {
        int g = base + i;
        if (g < total) rowptr[g] += add;
    }
}

__global__ void scatter_k(const int* __restrict__ edges, const int* __restrict__ rowptr,
                          int* __restrict__ cursor, int* __restrict__ csr) {
    int r = blockIdx.y;
    int e = blockIdx.x * 256 + threadIdx.x;
    int s = edges[(size_t)(2 * r) * NE + e];
    int d = edges[(size_t)(2 * r + 1) * NE + e];
    int pair = r * NN + d;
    int pos = atomicAdd(&cursor[pair], 1);
    csr[rowptr[pair] + pos] = s;
}

// ---------------- conversions / weight prep ----------------
__global__ void convert_x_k(const float* __restrict__ x, ushort_t* __restrict__ xb) {
    int idx = blockIdx.x * 256 + threadIdx.x;  // 100000*32 threads
    int n = idx >> 5;
    int c = idx & 31;
    float4 v = *(const float4*)(x + (size_t)n * 128 + c * 4);
    ushort4 o;
    o.x = f32_to_bf16(v.x); o.y = f32_to_bf16(v.y);
    o.z = f32_to_bf16(v.z); o.w = f32_to_bf16(v.w);
    *(ushort4*)(xb + (size_t)n * 128 + c * 4) = o;
}

// B1sT: 256x128 (sum of Wself1), B1nT: 7 x 256x128 (per-rel Wneigh1), b1s.
__global__ void prep_B1_k(const float* __restrict__ Wself, const float* __restrict__ Wneigh,
                          const float* __restrict__ b, ushort_t* __restrict__ BsT,
                          ushort_t* __restrict__ BnT, float* __restrict__ bs) {
    int idx = blockIdx.x * 256 + threadIdx.x;  // exactly 262400 threads
    if (idx < 32768) {
        int n = idx >> 7, k = idx & 127;
        float v = 0.f;
#pragma unroll
        for (int r = 0; r < 7; ++r) v += Wself[((size_t)r * 128 + k) * 256 + n];
        BsT[(size_t)n * 128 + k] = f32_to_bf16(v);
    } else if (idx < 262144) {
        int j = idx - 32768;
        int r = j >> 15;          // /32768
        int rem = j & 32767;
        int n = rem >> 7, k = rem & 127;
        BnT[j] = f32_to_bf16(Wneigh[((size_t)r * 128 + k) * 256 + n]);
    } else {
        int i = idx - 262144;     // < 256
        float s = 0.f;
#pragma unroll
        for (int r = 0; r < 7; ++r) s += b[r * 256 + i];
        bs[i] = s * (1.f / 7.f);
    }
}

// B2sT: 256x256 (sum of Wself2), B2nT: 7 x 256x256, b2s.
__global__ void prep_B2_k(const float* __restrict__ Wself, const float* __restrict__ Wneigh,
                          const float* __restrict__ b, ushort_t* __restrict__ BsT,
                          ushort_t* __restrict__ BnT, float* __restrict__ bs) {
    int idx = blockIdx.x * 256 + threadIdx.x;
    if (idx >= 524544) return;
    if (idx < 65536) {
        int n = idx >> 8, k = idx & 255;
        float v = 0.f;
#pragma unroll
        for (int r = 0; r < 7; ++r) v += Wself[((size_t)r * 256 + k) * 256 + n];
        BsT[(size_t)n * 256 + k] = f32_to_bf16(v);
    } else if (idx < 524288) {
        int j = idx - 65536;
        int r = j >> 16;
        int rem = j & 65535;
        int n = rem >> 8, k = rem & 255;
        BnT[j] = f32_to_bf16(Wneigh[((size_t)r * 256 + k) * 256 + n]);
    } else {
        int i = idx - 524288;     // < 256
        float s = 0.f;
#pragma unroll
        for (int r = 0; r < 7; ++r) s += b[r * 256 + i];
        bs[i] = s * (1.f / 7.f);
    }
}

__global__ void prep_cls_k(const float* __restrict__ Wc1, const float* __restrict__ bn_g,
                           const float* __restrict__ bn_b, const float* __restrict__ Wc2,
                           const float* __restrict__ bc2, ushort_t* __restrict__ Wc1T,
                           float* __restrict__ W2p, float* __restrict__ cp) {
    int idx = blockIdx.x * 256 + threadIdx.x;
    if (idx < 128 * 256) {
        int n = idx >> 8;
        int k = idx & 255;
        Wc1T[(size_t)n * 256 + k] = f32_to_bf16(Wc1[(size_t)k * 128 + n]);
    } else if (idx < 128 * 256 + 256) {
        int e = idx - 128 * 256;
        int d = e >> 1, j = e & 1;
        W2p[e] = bn_g[d] * rsqrtf(1.f + 1e-5f) * Wc2[d * 2 + j];
    } else if (idx < 128 * 256 + 256 + 2) {
        int j = idx - (128 * 256 + 256);
        float s = bc2[j];
        for (int d = 0; d < 128; ++d) s += bn_b[d] * Wc2[d * 2 + j];
        cp[j] = s;
    }
}

// ---------------- neighbor mean via CSR gather (one relation per launch) ----
// Row width = V*128 bf16. One wave per destination node.
template <int V>
__global__ __launch_bounds__(256) void gather_mean_k(
    const ushort_t* __restrict__ T, const int* __restrict__ csr,
    const int* __restrict__ rowptr, const int* __restrict__ deg,
    ushort_t* __restrict__ Mout, int r) {
    int n = blockIdx.x * 4 + (threadIdx.x >> 6);
    if (n >= NN) return;
    int lane = threadIdx.x & 63;
    int pair = r * NN + n;
    int start = rowptr[pair];
    int cnt = deg[pair];
    float acc[2 * V];
#pragma unroll
    for (int i = 0; i < 2 * V; ++i) acc[i] = 0.f;
    const uint* Tu = (const uint*)T;
    int s = (cnt > 0) ? csr[start] : 0;
    for (int j = 0; j < cnt; ++j) {
        int snext = (j + 1 < cnt) ? csr[start + j + 1] : 0;
        const uint* rowp = Tu + (size_t)s * (V * 64);
#pragma unroll
        for (int v = 0; v < V; ++v) {
            uint u = rowp[lane + v * 64];
            acc[2 * v] += bf16lo(u);
            acc[2 * v + 1] += bf16hi(u);
        }
        s = snext;
    }
    float inv = 1.f / (float)(cnt > 1 ? cnt : 1);
    uint* orow = (uint*)(Mout + (size_t)n * (V * 128));
#pragma unroll
    for (int v = 0; v < V; ++v) {
        uint lo = f32_to_bf16(acc[2 * v] * inv);
        uint hi = f32_to_bf16(acc[2 * v + 1] * inv);
        orow[lane + v * 64] = lo | (hi << 16);
    }
}

// ---------------- bf16 MFMA GEMM ----------------
// A: M x K row-major bf16 (lda); BT: N x K row-major bf16; C: M x N f32.
// accumulate=0: C = alpha*(A@BT^T) + bias (opt relu). accumulate=1: C += alpha*(A@BT^T).
__global__ __launch_bounds__(256) void gemm_bf16(
    const ushort_t* __restrict__ A, int lda, const ushort_t* __restrict__ BT,
    float* __restrict__ C, int M, int N, int K, float alpha,
    const float* __restrict__ bias, int relu, int accumulate) {
    __shared__ __align__(16) ushort_t lA[128 * 40];
    __shared__ __align__(16) ushort_t lB[128 * 40];
    int t = threadIdx.x;
    int gr0 = blockIdx.x * 128;
    int gc0 = blockIdx.y * 128;
    int w = t >> 6, lane = t & 63;
    int wr = w >> 1, wc = w & 1;
    int lm = lane & 15, quad = lane >> 4;
    f32x4 acc[4][4];
#pragma unroll
    for (int i = 0; i < 4; ++i)
#pragma unroll
        for (int j = 0; j < 4; ++j) acc[i][j] = (f32x4){0.f, 0.f, 0.f, 0.f};

    for (int kk = 0; kk < K; kk += 32) {
        __syncthreads();
#pragma unroll
        for (int p = 0; p < 2; ++p) {
            int idx = p * 256 + t;
            int row = idx >> 2;
            int slot = idx & 3;
            uint4 av = make_uint4(0, 0, 0, 0);
            if (gr0 + row < M)
                av = *(const uint4*)(A + (size_t)(gr0 + row) * lda + kk + slot * 8);
            *(uint4*)(lA + row * 40 + slot * 8) = av;
            uint4 bv = make_uint4(0, 0, 0, 0);
            if (gc0 + row < N)
                bv = *(const uint4*)(BT + (size_t)(gc0 + row) * K + kk + slot * 8);
            *(uint4*)(lB + row * 40 + slot * 8) = bv;
        }
        __syncthreads();
        bf16x8 af[4], bfr[4];
#pragma unroll
        for (int f = 0; f < 4; ++f) {
            af[f] = *(const bf16x8*)(lA + (wr * 64 + f * 16 + lm) * 40 + quad * 8);
            bfr[f] = *(const bf16x8*)(lB + (wc * 64 + f * 16 + lm) * 40 + quad * 8);
        }
#pragma unroll
        for (int fr = 0; fr < 4; ++fr)
#pragma unroll
            for (int fc = 0; fc < 4; ++fc)
                acc[fr][fc] = __builtin_amdgcn_mfma_f32_16x16x32_bf16(
                    af[fr], bfr[fc], acc[fr][fc], 0, 0, 0);
    }
#pragma unroll
    for (int fr = 0; fr < 4; ++fr) {
#pragma unroll
        for (int fc = 0; fc < 4; ++fc) {
#pragma unroll
            for (int i = 0; i < 4; ++i) {
                int row = wr * 64 + fr * 16 + quad * 4 + i;
                int col = wc * 64 + fc * 16 + lm;
                int gr = gr0 + row;
                int gc = gc0 + col;
                if (gr < M) {
                    size_t o = (size_t)gr * N + gc;
                    float v = acc[fr][fc][i] * alpha;
                    if (accumulate) v += C[o];
                    else v += (bias ? bias[gc] : 0.f);
                    if (relu) v = fmaxf(v, 0.f);
                    C[o] = v;
                }
            }
        }
    }
}

// ---------------- LayerNorm + ReLU -> bf16 (row = 256) ----------------
__global__ __launch_bounds__(256) void ln_relu_k(
    const float* __restrict__ h, const float* __restrict__ g,
    const float* __restrict__ b, ushort_t* __restrict__ out) {
    int n = blockIdx.x * 4 + (threadIdx.x >> 6);
    if (n >= NN) return;
    int lane = threadIdx.x & 63;
    const float* row = h + (size_t)n * 256;
    float4 v = *(const float4*)(row + lane * 4);
    float s = v.x + v.y + v.z + v.w;
    float q = v.x * v.x + v.y * v.y + v.z * v.z + v.w * v.w;
#pragma unroll
    for (int m = 1; m < 64; m <<= 1) {
        s += __shfl_xor(s, m);
        q += __shfl_xor(q, m);
    }
    float mean = s * (1.f / 256.f);
    float var = q * (1.f / 256.f) - mean * mean;
    float rs = rsqrtf(var + 1e-5f);
    float4 gv = *(const float4*)(g + lane * 4);
    float4 bv = *(const float4*)(b + lane * 4);
    float y0 = fmaxf((v.x - mean) * rs * gv.x + bv.x, 0.f);
    float y1 = fmaxf((v.y - mean) * rs * gv.y + bv.y, 0.f);
    float y2 = fmaxf((v.z - mean) * rs * gv.z + bv.z, 0.f);
    float y3 = fmaxf((v.w - mean) * rs * gv.w + bv.w, 0.f);
    uint2 o;
    o.x = (uint)f32_to_bf16(y0) | ((uint)f32_to_bf16(y1) << 16);
    o.y = (uint)f32_to_bf16(y2) | ((uint)f32_to_bf16(y3) << 16);
    *(uint2*)(out + (size_t)n * 256 + lane * 4) = o;
}

// ---------------- final 128 -> 2 with folded BN ----------------
__global__ __launch_bounds__(256) void final_k(const float* __restrict__ z1,
                                               const float* __restrict__ W2p,
                                               const float* __restrict__ cp,
                                               float* __restrict__ out) {
    int n = blockIdx.x * 4 + (threadIdx.x >> 6);
    if (n >= NN) return;
    int lane = threadIdx.x & 63;
    const float* zr = z1 + (size_t)n * 128;
    float z0 = zr[lane], z1v = zr[lane + 64];
    float a0 = z0 * W2p[lane * 2 + 0] + z1v * W2p[(lane + 64) * 2 + 0];
    float a1 = z0 * W2p[lane * 2 + 1] + z1v * W2p[(lane + 64) * 2 + 1];
#pragma unroll
    for (int m = 1; m < 64; m <<= 1) {
        a0 += __shfl_xor(a0, m);
        a1 += __shfl_xor(a1, m);
    }
    if (lane == 0) {
        out[(size_t)n * 2 + 0] = a0 + cp[0];
        out[(size_t)n * 2 + 1] = a1 + cp[1];
    }
}

// ---------------- workspace layout (~259.6 MB, offsets 256B-aligned) --------
constexpr size_t O_DEG  = 0;             // 7*100000*4 = 2,800,000 (pad 2,800,128)
constexpr size_t O_CUR  = 2800128;
constexpr size_t O_ROW  = 5600256;
constexpr size_t O_BLK  = 8400384;       // 171*4
constexpr size_t O_CSR  = 8401408;       // 11.2M*4 = 44,800,000
constexpr size_t O_B1ST = 53201408;      // 256*128*2 = 65,536
constexpr size_t O_B1NT = 53266944;      // 7*256*128*2 = 458,752
constexpr size_t O_B2ST = 53725696;      // 256*256*2 = 131,072
constexpr size_t O_B2NT = 53856768;      // 7*256*256*2 = 917,504
constexpr size_t O_WC1T = 54774272;      // 128*256*2 = 65,536
constexpr size_t O_W2P  = 54839808;      // 256*4
constexpr size_t O_CP   = 54840832;      // pad
constexpr size_t O_B1S  = 54841088;      // 256*4
constexpr size_t O_B2S  = 54842112;      // 256*4
constexpr size_t O_X    = 54843136;      // x_bf16 100k*128*2 = 25,600,000
constexpr size_t O_M1   = 80443136;      // mean1 100k*128*2 = 25,600,000
// mean2 / h2b (100k*256*2 = 51,200,000) alias O_X..O_H1B (x & mean1 dead)
constexpr size_t O_H1B  = 106043136;     // h1b 100k*256*2 = 51,200,000
constexpr size_t O_HACC = 157243136;     // hacc 100k*256*4 = 102,400,000
// z1 (100k*128*4 = 51,200,000) aliases O_HACC (hacc dead after LN2)
constexpr size_t WS_REQUIRED = 259643136;

extern "C" void kernel_launch(void* const* d_in, const int* in_sizes, int n_in,
                              void* d_out, int out_size, void* d_ws, size_t ws_size,
                              hipStream_t stream) {
    (void)in_sizes; (void)n_in;
    const float* features = (const float*)d_in[0];
    const int* edges = (const int*)d_in[1];
    const float* Wself1 = (const float*)d_in[2];
    const float* Wneigh1 = (const float*)d_in[3];
    const float* b1 = (const float*)d_in[4];
    const float* Wself2 = (const float*)d_in[5];
    const float* Wneigh2 = (const float*)d_in[6];
    const float* b2 = (const float*)d_in[7];
    const float* ln_g = (const float*)d_in[8];
    const float* ln_b = (const float*)d_in[9];
    const float* Wc1 = (const float*)d_in[10];
    const float* bc1 = (const float*)d_in[11];
    const float* bn_g = (const float*)d_in[12];
    const float* bn_b = (const float*)d_in[13];
    const float* Wc2 = (const float*)d_in[14];
    const float* bc2 = (const float*)d_in[15];
    float* out = (float*)d_out;
    char* ws = (char*)d_ws;

    if (ws_size < WS_REQUIRED) {
        // Workspace too small for this design — sentinel: zero output, bail.
        hipMemsetAsync(d_out, 0, (size_t)out_size * 4, stream);
        return;
    }

    int* deg = (int*)(ws + O_DEG);
    int* cursor = (int*)(ws + O_CUR);
    int* rowptr = (int*)(ws + O_ROW);
    int* blk = (int*)(ws + O_BLK);
    int* csr = (int*)(ws + O_CSR);
    ushort_t* B1sT = (ushort_t*)(ws + O_B1ST);
    ushort_t* B1nT = (ushort_t*)(ws + O_B1NT);
    ushort_t* B2sT = (ushort_t*)(ws + O_B2ST);
    ushort_t* B2nT = (ushort_t*)(ws + O_B2NT);
    ushort_t* Wc1T = (ushort_t*)(ws + O_WC1T);
    float* W2p = (float*)(ws + O_W2P);
    float* cp = (float*)(ws + O_CP);
    float* b1s = (float*)(ws + O_B1S);
    float* b2s = (float*)(ws + O_B2S);
    ushort_t* xb = (ushort_t*)(ws + O_X);
    ushort_t* mean1 = (ushort_t*)(ws + O_M1);
    ushort_t* mean2 = (ushort_t*)(ws + O_X);   // alias: x & mean1 dead in layer 2
    ushort_t* h2b = (ushort_t*)(ws + O_X);     // alias: mean2 dead after layer 2
    ushort_t* h1b = (ushort_t*)(ws + O_H1B);
    float* hacc = (float*)(ws + O_HACC);
    float* z1 = (float*)(ws + O_HACC);         // alias: hacc dead after LN2

    // zero deg + cursor (adjacent regions)
    hipMemsetAsync(ws + O_DEG, 0, O_ROW - O_DEG, stream);

    // CSR build (shared by both layers)
    deg_k<<<dim3(6250, 7, 1), 256, 0, stream>>>(edges, deg);
    scan1_k<<<171, 256, 0, stream>>>(deg, rowptr, blk, NREL * NN);
    scan2_k<<<1, 64, 0, stream>>>(blk, 171);
    scan3_k<<<171, 256, 0, stream>>>(rowptr, blk, NREL * NN);
    scatter_k<<<dim3(6250, 7, 1), 256, 0, stream>>>(edges, rowptr, cursor, csr);

    // weight prep + x -> bf16
    convert_x_k<<<12500, 256, 0, stream>>>(features, xb);
    prep_B1_k<<<1025, 256, 0, stream>>>(Wself1, Wneigh1, b1, B1sT, B1nT, b1s);
    prep_B2_k<<<2050, 256, 0, stream>>>(Wself2, Wneigh2, b2, B2sT, B2nT, b2s);
    prep_cls_k<<<130, 256, 0, stream>>>(Wc1, bn_g, bn_b, Wc2, bc2, Wc1T, W2p, cp);

    // ---- layer 1: hacc = (1/7)[x@sumWself1 + sum_r mean_r@Wneigh1_r] + b1s
    gemm_bf16<<<dim3(782, 2, 1), 256, 0, stream>>>(xb, 128, B1sT, hacc,
                                                   NN, 256, 128, 1.f / 7.f, b1s, 0, 0);
    for (int r = 0; r < NREL; ++r) {
        gather_mean_k<1><<<25000, 256, 0, stream>>>(xb, csr, rowptr, deg, mean1, r);
        gemm_bf16<<<dim3(782, 2, 1), 256, 0, stream>>>(mean1, 128, B1nT + (size_t)r * 32768,
                                                       hacc, NN, 256, 128, 1.f / 7.f,
                                                       nullptr, 0, 1);
    }
    ln_relu_k<<<25000, 256, 0, stream>>>(hacc, ln_g, ln_b, h1b);

    // ---- layer 2
    gemm_bf16<<<dim3(782, 2, 1), 256, 0, stream>>>(h1b, 256, B2sT, hacc,
                                                   NN, 256, 256, 1.f / 7.f, b2s, 0, 0);
    for (int r = 0; r < NREL; ++r) {
        gather_mean_k<2><<<25000, 256, 0, stream>>>(h1b, csr, rowptr, deg, mean2, r);
        gemm_bf16<<<dim3(782, 2, 1), 256, 0, stream>>>(mean2, 256, B2nT + (size_t)r * 65536,
                                                       hacc, NN, 256, 256, 1.f / 7.f,
                                                       nullptr, 0, 1);
    }
    ln_relu_k<<<25000, 256, 0, stream>>>(hacc, ln_g + 256, ln_b + 256, h2b);

    // ---- classifier
    gemm_bf16<<<dim3(782, 1, 1), 256, 0, stream>>>(h2b, 256, Wc1T, z1,
                                                   NN, 128, 256, 1.f, bc1, 1, 0);
    final_k<<<25000, 256, 0, stream>>>(z1, W2p, cp, out);
}

// Round 3
// 3832.874 us; speedup vs baseline: 1.2785x; 1.2785x over previous
//
#include <hip/hip_runtime.h>
#include <hip/hip_bf16.h>
#include <cstdint>

// ---------------------------------------------------------------------------
// HeteroGNN: 2-layer hetero-SAGE (7 rel, 1.6M edges) + classifier, 100k nodes.
// Design C2:
//  * CSR build: LDS-binned bucket pass (coalesced writes, fused degree
//    histogram) -> scan -> L2-local per-bucket scatter. Fixes the 16x write
//    amplification of the naive scatter (750 MB -> ~90 MB).
//  * Per relation r: gather_mean (CSR, 4-wide unrolled for MLP) -> GEMM
//    accumulating hacc += (1/7) * mean_r @ Wneigh[r] (fp32, L3-resident).
//  * Self term: one GEMM per layer with pre-summed sum_r Wself[r].
//  * bf16 MFMA 16x16x32, 128x128 tiles, fp32 accumulate.
// Workspace ~259.6 MB (bucket pairs buffer aliases h1b/hacc region).
// ---------------------------------------------------------------------------

#define NN 100000
#define NREL 7
#define NE 1600000
#define NB 64            // buckets per relation
#define BCAP 28672       // slots per bucket (mean 25006, +23 sigma safe)
#define BNODES 1563      // ceil(100000/64)

using uint = unsigned int;
using ushort_t = unsigned short;
using bf16x8 = __attribute__((ext_vector_type(8))) __bf16;
using f32x4 = __attribute__((ext_vector_type(4))) float;

__device__ __forceinline__ ushort_t f32_to_bf16(float f) {
    uint u = __float_as_uint(f);
    u += 0x7fffu + ((u >> 16) & 1u);
    return (ushort_t)(u >> 16);
}
__device__ __forceinline__ float bf16lo(uint u) { return __uint_as_float(u << 16); }
__device__ __forceinline__ float bf16hi(uint u) { return __uint_as_float(u & 0xffff0000u); }

// ---------------- CSR build: pass 1 — LDS bucket binning + degree ----------
// Block: 256 threads x 16 edges = 4096 edge slots. Grid: (391, 7).
__global__ __launch_bounds__(256) void binpass_k(const int* __restrict__ edges,
                                                 int* __restrict__ deg,
                                                 int* __restrict__ bcnt,
                                                 uint2* __restrict__ bbuf) {
    __shared__ int cnt[NB];
    __shared__ int lofs[NB];
    __shared__ int gbase[NB];
    __shared__ int stotal;
    __shared__ uint2 stage[4096];       // 32 KB
    __shared__ unsigned char bb[4096];  // 4 KB
    int r = blockIdx.y;
    int t = threadIdx.x;
    if (t < NB) cnt[t] = 0;
    __syncthreads();
    int e0 = blockIdx.x * 4096;
    uint2 mypair[16];
    int myrb[16];  // (rank<<6)|b, or -1 invalid
    // Phase A: read edges (coalesced), LDS-rank per bucket, degree histogram.
#pragma unroll
    for (int i = 0; i < 16; ++i) {
        int e = e0 + i * 256 + t;
        if (e < NE) {
            int s = edges[(size_t)(2 * r) * NE + e];
            int d = edges[(size_t)(2 * r + 1) * NE + e];
            int b = d / BNODES;
            int rank = atomicAdd(&cnt[b], 1);
            myrb[i] = (rank << 6) | b;
            mypair[i] = make_uint2((uint)s, (uint)d);
            atomicAdd(&deg[r * NN + d], 1);
        } else {
            myrb[i] = -1;
        }
    }
    __syncthreads();
    // Phase B: exclusive prefix over 64 buckets (wave 0) + global reservation.
    if (t < 64) {
        int c = cnt[t];
        int x = c;
#pragma unroll
        for (int off = 1; off < 64; off <<= 1) {
            int y = __shfl_up(x, off);
            if (t >= off) x += y;
        }
        lofs[t] = x - c;
        gbase[t] = atomicAdd(&bcnt[r * NB + t], c);
        if (t == 63) stotal = x;
    }
    __syncthreads();
    // Phase C: stage pairs bucket-sorted in LDS.
#pragma unroll
    for (int i = 0; i < 16; ++i) {
        if (myrb[i] >= 0) {
            int b = myrb[i] & 63;
            int p = lofs[b] + (myrb[i] >> 6);
            stage[p] = mypair[i];
            bb[p] = (unsigned char)b;
        }
    }
    __syncthreads();
    // Phase D: write out bucket-contiguous runs (coalesced).
    int total = stotal;
    for (int p = t; p < total; p += 256) {
        int b = bb[p];
        uint2 pr = stage[p];
        int gpos = gbase[b] + (p - lofs[b]);
        if (gpos < BCAP)
            bbuf[((size_t)r * NB + b) * BCAP + gpos] = pr;
    }
}

// ---------------- CSR build: scan (deg -> rowptr) ----------------
__global__ void scan1_k(const int* __restrict__ deg, int* __restrict__ rowptr,
                        int* __restrict__ blk, int total) {
    __shared__ int wsum[4];
    int t = threadIdx.x;
    int base = blockIdx.x * 4096 + t * 16;
    int vals[16];
    int s = 0;
#pragma unroll
    for (int i = 0; i < 16; ++i) {
        int g = base + i;
        int v = (g < total) ? deg[g] : 0;
        vals[i] = s;
        s += v;
    }
    int lane = t & 63, w = t >> 6;
    int x = s;
    for (int off = 1; off < 64; off <<= 1) {
        int y = __shfl_up(x, off);
        if (lane >= off) x += y;
    }
    if (lane == 63) wsum[w] = x;
    __syncthreads();
    if (t == 0) {
        int a = 0;
#pragma unroll
        for (int k = 0; k < 4; ++k) { int b = wsum[k]; wsum[k] = a; a += b; }
        blk[blockIdx.x] = a;
    }
    __syncthreads();
    int excl = x - s + wsum[w];
#pragma unroll
    for (int i = 0; i < 16; ++i) {
        int g = base + i;
        if (g < total) rowptr[g] = excl + vals[i];
    }
}

__global__ void scan2_k(int* blk, int nb) {
    if (threadIdx.x == 0 && blockIdx.x == 0) {
        int a = 0;
        for (int i = 0; i < nb; ++i) { int b = blk[i]; blk[i] = a; a += b; }
    }
}

__global__ void scan3_k(int* __restrict__ rowptr, const int* __restrict__ blk, int total) {
    int t = threadIdx.x;
    int add = blk[blockIdx.x];
    int base = blockIdx.x * 4096 + t * 16;
#pragma unroll
    for (int i = 0; i < 16; ++i) {
        int g = base + i;
        if (g < total) rowptr[g] += add;
    }
}

// ---------------- CSR build: pass 2 — L2-local per-bucket scatter ----------
// One 1024-thread block per (relation, bucket): csr window ~100 KB, cursor
// window ~6 KB -> L2-resident on one XCD, writebacks amortize to full lines.
__global__ __launch_bounds__(1024) void scatter2_k(const uint2* __restrict__ bbuf,
                                                   const int* __restrict__ bcnt,
                                                   const int* __restrict__ rowptr,
                                                   int* __restrict__ cursor,
                                                   int* __restrict__ csr) {
    int rb = blockIdx.x;
    int r = rb >> 6;
    int cb = bcnt[rb];
    if (cb > BCAP) cb = BCAP;
    const uint2* src = bbuf + (size_t)rb * BCAP;
    for (int i = threadIdx.x; i < cb; i += 1024) {
        uint2 p = src[i];
        int pair = r * NN + (int)p.y;
        int pos = atomicAdd(&cursor[pair], 1);
        csr[rowptr[pair] + pos] = (int)p.x;
    }
}

// ---------------- conversions / weight prep ----------------
__global__ void convert_x_k(const float* __restrict__ x, ushort_t* __restrict__ xb) {
    int idx = blockIdx.x * 256 + threadIdx.x;  // 100000*32 threads
    int n = idx >> 5;
    int c = idx & 31;
    float4 v = *(const float4*)(x + (size_t)n * 128 + c * 4);
    ushort4 o;
    o.x = f32_to_bf16(v.x); o.y = f32_to_bf16(v.y);
    o.z = f32_to_bf16(v.z); o.w = f32_to_bf16(v.w);
    *(ushort4*)(xb + (size_t)n * 128 + c * 4) = o;
}

__global__ void prep_B1_k(const float* __restrict__ Wself, const float* __restrict__ Wneigh,
                          const float* __restrict__ b, ushort_t* __restrict__ BsT,
                          ushort_t* __restrict__ BnT, float* __restrict__ bs) {
    int idx = blockIdx.x * 256 + threadIdx.x;  // 262400 threads
    if (idx < 32768) {
        int n = idx >> 7, k = idx & 127;
        float v = 0.f;
#pragma unroll
        for (int r = 0; r < 7; ++r) v += Wself[((size_t)r * 128 + k) * 256 + n];
        BsT[(size_t)n * 128 + k] = f32_to_bf16(v);
    } else if (idx < 262144) {
        int j = idx - 32768;
        int r = j >> 15;
        int rem = j & 32767;
        int n = rem >> 7, k = rem & 127;
        BnT[j] = f32_to_bf16(Wneigh[((size_t)r * 128 + k) * 256 + n]);
    } else {
        int i = idx - 262144;
        float s = 0.f;
#pragma unroll
        for (int r = 0; r < 7; ++r) s += b[r * 256 + i];
        bs[i] = s * (1.f / 7.f);
    }
}

__global__ void prep_B2_k(const float* __restrict__ Wself, const float* __restrict__ Wneigh,
                          const float* __restrict__ b, ushort_t* __restrict__ BsT,
                          ushort_t* __restrict__ BnT, float* __restrict__ bs) {
    int idx = blockIdx.x * 256 + threadIdx.x;
    if (idx >= 524544) return;
    if (idx < 65536) {
        int n = idx >> 8, k = idx & 255;
        float v = 0.f;
#pragma unroll
        for (int r = 0; r < 7; ++r) v += Wself[((size_t)r * 256 + k) * 256 + n];
        BsT[(size_t)n * 256 + k] = f32_to_bf16(v);
    } else if (idx < 524288) {
        int j = idx - 65536;
        int r = j >> 16;
        int rem = j & 65535;
        int n = rem >> 8, k = rem & 255;
        BnT[j] = f32_to_bf16(Wneigh[((size_t)r * 256 + k) * 256 + n]);
    } else {
        int i = idx - 524288;
        float s = 0.f;
#pragma unroll
        for (int r = 0; r < 7; ++r) s += b[r * 256 + i];
        bs[i] = s * (1.f / 7.f);
    }
}

__global__ void prep_cls_k(const float* __restrict__ Wc1, const float* __restrict__ bn_g,
                           const float* __restrict__ bn_b, const float* __restrict__ Wc2,
                           const float* __restrict__ bc2, ushort_t* __restrict__ Wc1T,
                           float* __restrict__ W2p, float* __restrict__ cp) {
    int idx = blockIdx.x * 256 + threadIdx.x;
    if (idx < 128 * 256) {
        int n = idx >> 8;
        int k = idx & 255;
        Wc1T[(size_t)n * 256 + k] = f32_to_bf16(Wc1[(size_t)k * 128 + n]);
    } else if (idx < 128 * 256 + 256) {
        int e = idx - 128 * 256;
        int d = e >> 1, j = e & 1;
        W2p[e] = bn_g[d] * rsqrtf(1.f + 1e-5f) * Wc2[d * 2 + j];
    } else if (idx < 128 * 256 + 256 + 2) {
        int j = idx - (128 * 256 + 256);
        float s = bc2[j];
        for (int d = 0; d < 128; ++d) s += bn_b[d] * Wc2[d * 2 + j];
        cp[j] = s;
    }
}

// ---------------- neighbor mean via CSR gather, 4-wide MLP unroll ----------
// Row width = V*128 bf16 (V*64 uints). One wave per destination node.
template <int V>
__global__ __launch_bounds__(256) void gather_mean_k(
    const ushort_t* __restrict__ T, const int* __restrict__ csr,
    const int* __restrict__ rowptr, const int* __restrict__ deg,
    ushort_t* __restrict__ Mout, int r) {
    int n = blockIdx.x * 4 + (threadIdx.x >> 6);
    if (n >= NN) return;
    int lane = threadIdx.x & 63;
    int pair = r * NN + n;
    int start = rowptr[pair];
    int cnt = deg[pair];
    const uint* Tu = (const uint*)T;
    float a0[2 * V], a1[2 * V], a2[2 * V], a3[2 * V];
#pragma unroll
    for (int i = 0; i < 2 * V; ++i) { a0[i] = 0.f; a1[i] = 0.f; a2[i] = 0.f; a3[i] = 0.f; }
    int j = 0;
    for (; j + 4 <= cnt; j += 4) {
        int s0 = csr[start + j];
        int s1 = csr[start + j + 1];
        int s2 = csr[start + j + 2];
        int s3 = csr[start + j + 3];
        const uint* r0 = Tu + (size_t)s0 * (V * 64);
        const uint* r1 = Tu + (size_t)s1 * (V * 64);
        const uint* r2 = Tu + (size_t)s2 * (V * 64);
        const uint* r3 = Tu + (size_t)s3 * (V * 64);
        uint u0[V], u1[V], u2[V], u3[V];
#pragma unroll
        for (int v = 0; v < V; ++v) {
            u0[v] = r0[lane + v * 64];
            u1[v] = r1[lane + v * 64];
            u2[v] = r2[lane + v * 64];
            u3[v] = r3[lane + v * 64];
        }
#pragma unroll
        for (int v = 0; v < V; ++v) {
            a0[2 * v] += bf16lo(u0[v]); a0[2 * v + 1] += bf16hi(u0[v]);
            a1[2 * v] += bf16lo(u1[v]); a1[2 * v + 1] += bf16hi(u1[v]);
            a2[2 * v] += bf16lo(u2[v]); a2[2 * v + 1] += bf16hi(u2[v]);
            a3[2 * v] += bf16lo(u3[v]); a3[2 * v + 1] += bf16hi(u3[v]);
        }
    }
    for (; j < cnt; ++j) {
        int s = csr[start + j];
        const uint* rp = Tu + (size_t)s * (V * 64);
#pragma unroll
        for (int v = 0; v < V; ++v) {
            uint u = rp[lane + v * 64];
            a0[2 * v] += bf16lo(u);
            a0[2 * v + 1] += bf16hi(u);
        }
    }
    float inv = 1.f / (float)(cnt > 1 ? cnt : 1);
    uint* orow = (uint*)(Mout + (size_t)n * (V * 128));
#pragma unroll
    for (int v = 0; v < V; ++v) {
        float lo = (a0[2 * v] + a1[2 * v]) + (a2[2 * v] + a3[2 * v]);
        float hi = (a0[2 * v + 1] + a1[2 * v + 1]) + (a2[2 * v + 1] + a3[2 * v + 1]);
        uint l = f32_to_bf16(lo * inv);
        uint h = f32_to_bf16(hi * inv);
        orow[lane + v * 64] = l | (h << 16);
    }
}

// ---------------- bf16 MFMA GEMM ----------------
// A: M x K row-major bf16 (lda); BT: N x K row-major bf16; C: M x N f32.
// accumulate=0: C = alpha*(A@BT^T) + bias (opt relu). accumulate=1: C += alpha*(A@BT^T).
__global__ __launch_bounds__(256) void gemm_bf16(
    const ushort_t* __restrict__ A, int lda, const ushort_t* __restrict__ BT,
    float* __restrict__ C, int M, int N, int K, float alpha,
    const float* __restrict__ bias, int relu, int accumulate) {
    __shared__ __align__(16) ushort_t lA[128 * 40];
    __shared__ __align__(16) ushort_t lB[128 * 40];
    int t = threadIdx.x;
    int gr0 = blockIdx.x * 128;
    int gc0 = blockIdx.y * 128;
    int w = t >> 6, lane = t & 63;
    int wr = w >> 1, wc = w & 1;
    int lm = lane & 15, quad = lane >> 4;
    f32x4 acc[4][4];
#pragma unroll
    for (int i = 0; i < 4; ++i)
#pragma unroll
        for (int j = 0; j < 4; ++j) acc[i][j] = (f32x4){0.f, 0.f, 0.f, 0.f};

    for (int kk = 0; kk < K; kk += 32) {
        __syncthreads();
#pragma unroll
        for (int p = 0; p < 2; ++p) {
            int idx = p * 256 + t;
            int row = idx >> 2;
            int slot = idx & 3;
            uint4 av = make_uint4(0, 0, 0, 0);
            if (gr0 + row < M)
                av = *(const uint4*)(A + (size_t)(gr0 + row) * lda + kk + slot * 8);
            *(uint4*)(lA + row * 40 + slot * 8) = av;
            uint4 bv = make_uint4(0, 0, 0, 0);
            if (gc0 + row < N)
                bv = *(const uint4*)(BT + (size_t)(gc0 + row) * K + kk + slot * 8);
            *(uint4*)(lB + row * 40 + slot * 8) = bv;
        }
        __syncthreads();
        bf16x8 af[4], bfr[4];
#pragma unroll
        for (int f = 0; f < 4; ++f) {
            af[f] = *(const bf16x8*)(lA + (wr * 64 + f * 16 + lm) * 40 + quad * 8);
            bfr[f] = *(const bf16x8*)(lB + (wc * 64 + f * 16 + lm) * 40 + quad * 8);
        }
#pragma unroll
        for (int fr = 0; fr < 4; ++fr)
#pragma unroll
            for (int fc = 0; fc < 4; ++fc)
                acc[fr][fc] = __builtin_amdgcn_mfma_f32_16x16x32_bf16(
                    af[fr], bfr[fc], acc[fr][fc], 0, 0, 0);
    }
#pragma unroll
    for (int fr = 0; fr < 4; ++fr) {
#pragma unroll
        for (int fc = 0; fc < 4; ++fc) {
#pragma unroll
            for (int i = 0; i < 4; ++i) {
                int row = wr * 64 + fr * 16 + quad * 4 + i;
                int col = wc * 64 + fc * 16 + lm;
                int gr = gr0 + row;
                int gc = gc0 + col;
                if (gr < M) {
                    size_t o = (size_t)gr * N + gc;
                    float v = acc[fr][fc][i] * alpha;
                    if (accumulate) v += C[o];
                    else v += (bias ? bias[gc] : 0.f);
                    if (relu) v = fmaxf(v, 0.f);
                    C[o] = v;
                }
            }
        }
    }
}

// ---------------- LayerNorm + ReLU -> bf16 (row = 256) ----------------
__global__ __launch_bounds__(256) void ln_relu_k(
    const float* __restrict__ h, const float* __restrict__ g,
    const float* __restrict__ b, ushort_t* __restrict__ out) {
    int n = blockIdx.x * 4 + (threadIdx.x >> 6);
    if (n >= NN) return;
    int lane = threadIdx.x & 63;
    const float* row = h + (size_t)n * 256;
    float4 v = *(const float4*)(row + lane * 4);
    float s = v.x + v.y + v.z + v.w;
    float q = v.x * v.x + v.y * v.y + v.z * v.z + v.w * v.w;
#pragma unroll
    for (int m = 1; m < 64; m <<= 1) {
        s += __shfl_xor(s, m);
        q += __shfl_xor(q, m);
    }
    float mean = s * (1.f / 256.f);
    float var = q * (1.f / 256.f) - mean * mean;
    float rs = rsqrtf(var + 1e-5f);
    float4 gv = *(const float4*)(g + lane * 4);
    float4 bv = *(const float4*)(b + lane * 4);
    float y0 = fmaxf((v.x - mean) * rs * gv.x + bv.x, 0.f);
    float y1 = fmaxf((v.y - mean) * rs * gv.y + bv.y, 0.f);
    float y2 = fmaxf((v.z - mean) * rs * gv.z + bv.z, 0.f);
    float y3 = fmaxf((v.w - mean) * rs * gv.w + bv.w, 0.f);
    uint2 o;
    o.x = (uint)f32_to_bf16(y0) | ((uint)f32_to_bf16(y1) << 16);
    o.y = (uint)f32_to_bf16(y2) | ((uint)f32_to_bf16(y3) << 16);
    *(uint2*)(out + (size_t)n * 256 + lane * 4) = o;
}

// ---------------- final 128 -> 2 with folded BN ----------------
__global__ __launch_bounds__(256) void final_k(const float* __restrict__ z1,
                                               const float* __restrict__ W2p,
                                               const float* __restrict__ cp,
                                               float* __restrict__ out) {
    int n = blockIdx.x * 4 + (threadIdx.x >> 6);
    if (n >= NN) return;
    int lane = threadIdx.x & 63;
    const float* zr = z1 + (size_t)n * 128;
    float z0 = zr[lane], z1v = zr[lane + 64];
    float a0 = z0 * W2p[lane * 2 + 0] + z1v * W2p[(lane + 64) * 2 + 0];
    float a1 = z0 * W2p[lane * 2 + 1] + z1v * W2p[(lane + 64) * 2 + 1];
#pragma unroll
    for (int m = 1; m < 64; m <<= 1) {
        a0 += __shfl_xor(a0, m);
        a1 += __shfl_xor(a1, m);
    }
    if (lane == 0) {
        out[(size_t)n * 2 + 0] = a0 + cp[0];
        out[(size_t)n * 2 + 1] = a1 + cp[1];
    }
}

// ---------------- workspace layout (~259.6 MB, offsets 256B-aligned) --------
constexpr size_t O_DEG  = 0;             // 7*100000*4 = 2,800,000 (pad 2,800,128)
constexpr size_t O_CUR  = 2800128;
constexpr size_t O_ROW  = 5600256;
constexpr size_t O_BLK  = 8400384;       // 171*4
constexpr size_t O_CSR  = 8401408;       // 11.2M*4 = 44,800,000
constexpr size_t O_B1ST = 53201408;      // 256*128*2
constexpr size_t O_B1NT = 53266944;      // 7*256*128*2
constexpr size_t O_B2ST = 53725696;      // 256*256*2
constexpr size_t O_B2NT = 53856768;      // 7*256*256*2
constexpr size_t O_WC1T = 54774272;      // 128*256*2
constexpr size_t O_W2P  = 54839808;
constexpr size_t O_CP   = 54840832;
constexpr size_t O_B1S  = 54841088;
constexpr size_t O_B2S  = 54842112;
constexpr size_t O_X    = 54843136;      // x_bf16 100k*128*2 = 25,600,000
constexpr size_t O_M1   = 80443136;      // mean1 100k*128*2 = 25,600,000
constexpr size_t O_H1B  = 106043136;     // h1b 100k*256*2 = 51,200,000
constexpr size_t O_HACC = 157243136;     // hacc 100k*256*4 = 102,400,000
// bucket-pass scratch (CSR-build lifetime only, before h1b/hacc live):
constexpr size_t O_BCNT = O_H1B;                   // 448*4 (pad 2048)
constexpr size_t O_BBUF = O_H1B + 2048;            // 7*64*28672*8 = 102,760,448
constexpr size_t WS_REQUIRED = 259643136;

extern "C" void kernel_launch(void* const* d_in, const int* in_sizes, int n_in,
                              void* d_out, int out_size, void* d_ws, size_t ws_size,
                              hipStream_t stream) {
    (void)in_sizes; (void)n_in;
    const float* features = (const float*)d_in[0];
    const int* edges = (const int*)d_in[1];
    const float* Wself1 = (const float*)d_in[2];
    const float* Wneigh1 = (const float*)d_in[3];
    const float* b1 = (const float*)d_in[4];
    const float* Wself2 = (const float*)d_in[5];
    const float* Wneigh2 = (const float*)d_in[6];
    const float* b2 = (const float*)d_in[7];
    const float* ln_g = (const float*)d_in[8];
    const float* ln_b = (const float*)d_in[9];
    const float* Wc1 = (const float*)d_in[10];
    const float* bc1 = (const float*)d_in[11];
    const float* bn_g = (const float*)d_in[12];
    const float* bn_b = (const float*)d_in[13];
    const float* Wc2 = (const float*)d_in[14];
    const float* bc2 = (const float*)d_in[15];
    float* out = (float*)d_out;
    char* ws = (char*)d_ws;

    if (ws_size < WS_REQUIRED) {
        hipMemsetAsync(d_out, 0, (size_t)out_size * 4, stream);
        return;
    }

    int* deg = (int*)(ws + O_DEG);
    int* cursor = (int*)(ws + O_CUR);
    int* rowptr = (int*)(ws + O_ROW);
    int* blk = (int*)(ws + O_BLK);
    int* csr = (int*)(ws + O_CSR);
    ushort_t* B1sT = (ushort_t*)(ws + O_B1ST);
    ushort_t* B1nT = (ushort_t*)(ws + O_B1NT);
    ushort_t* B2sT = (ushort_t*)(ws + O_B2ST);
    ushort_t* B2nT = (ushort_t*)(ws + O_B2NT);
    ushort_t* Wc1T = (ushort_t*)(ws + O_WC1T);
    float* W2p = (float*)(ws + O_W2P);
    float* cp = (float*)(ws + O_CP);
    float* b1s = (float*)(ws + O_B1S);
    float* b2s = (float*)(ws + O_B2S);
    ushort_t* xb = (ushort_t*)(ws + O_X);
    ushort_t* mean1 = (ushort_t*)(ws + O_M1);
    ushort_t* mean2 = (ushort_t*)(ws + O_X);   // alias: x & mean1 dead in layer 2
    ushort_t* h2b = (ushort_t*)(ws + O_X);     // alias: mean2 dead after layer 2
    ushort_t* h1b = (ushort_t*)(ws + O_H1B);
    float* hacc = (float*)(ws + O_HACC);
    float* z1 = (float*)(ws + O_HACC);         // alias: hacc dead after LN2
    int* bcnt = (int*)(ws + O_BCNT);
    uint2* bbuf = (uint2*)(ws + O_BBUF);

    // zero deg + cursor (adjacent) and bucket counters
    hipMemsetAsync(ws + O_DEG, 0, O_ROW - O_DEG, stream);
    hipMemsetAsync(ws + O_BCNT, 0, 2048, stream);

    // CSR build (shared by both layers)
    binpass_k<<<dim3(391, 7, 1), 256, 0, stream>>>(edges, deg, bcnt, bbuf);
    scan1_k<<<171, 256, 0, stream>>>(deg, rowptr, blk, NREL * NN);
    scan2_k<<<1, 64, 0, stream>>>(blk, 171);
    scan3_k<<<171, 256, 0, stream>>>(rowptr, blk, NREL * NN);
    scatter2_k<<<448, 1024, 0, stream>>>(bbuf, bcnt, rowptr, cursor, csr);

    // weight prep + x -> bf16
    convert_x_k<<<12500, 256, 0, stream>>>(features, xb);
    prep_B1_k<<<1025, 256, 0, stream>>>(Wself1, Wneigh1, b1, B1sT, B1nT, b1s);
    prep_B2_k<<<2050, 256, 0, stream>>>(Wself2, Wneigh2, b2, B2sT, B2nT, b2s);
    prep_cls_k<<<130, 256, 0, stream>>>(Wc1, bn_g, bn_b, Wc2, bc2, Wc1T, W2p, cp);

    // ---- layer 1: hacc = (1/7)[x@sumWself1 + sum_r mean_r@Wneigh1_r] + b1s
    gemm_bf16<<<dim3(782, 2, 1), 256, 0, stream>>>(xb, 128, B1sT, hacc,
                                                   NN, 256, 128, 1.f / 7.f, b1s, 0, 0);
    for (int r = 0; r < NREL; ++r) {
        gather_mean_k<1><<<25000, 256, 0, stream>>>(xb, csr, rowptr, deg, mean1, r);
        gemm_bf16<<<dim3(782, 2, 1), 256, 0, stream>>>(mean1, 128, B1nT + (size_t)r * 32768,
                                                       hacc, NN, 256, 128, 1.f / 7.f,
                                                       nullptr, 0, 1);
    }
    ln_relu_k<<<25000, 256, 0, stream>>>(hacc, ln_g, ln_b, h1b);

    // ---- layer 2
    gemm_bf16<<<dim3(782, 2, 1), 256, 0, stream>>>(h1b, 256, B2sT, hacc,
                                                   NN, 256, 256, 1.f / 7.f, b2s, 0, 0);
    for (int r = 0; r < NREL; ++r) {
        gather_mean_k<2><<<25000, 256, 0, stream>>>(h1b, csr, rowptr, deg, mean2, r);
        gemm_bf16<<<dim3(782, 2, 1), 256, 0, stream>>>(mean2, 256, B2nT + (size_t)r * 65536,
                                                       hacc, NN, 256, 256, 1.f / 7.f,
                                                       nullptr, 0, 1);
    }
    ln_relu_k<<<25000, 256, 0, stream>>>(hacc, ln_g + 256, ln_b + 256, h2b);

    // ---- classifier
    gemm_bf16<<<dim3(782, 1, 1), 256, 0, stream>>>(h2b, 256, Wc1T, z1,
                                                   NN, 128, 256, 1.f, bc1, 1, 0);
    final_k<<<25000, 256, 0, stream>>>(z1, W2p, cp, out);
}

// Round 4
// 3070.540 us; speedup vs baseline: 1.5960x; 1.2483x over previous
//
#include <hip/hip_runtime.h>
#include <hip/hip_bf16.h>
#include <cstdint>

// ---------------------------------------------------------------------------
// HeteroGNN: 2-layer hetero-SAGE (7 rel, 1.6M edges) + classifier, 100k nodes.
// Design C3:
//  * CSR build, fully coalesced: binpass (LDS bucket binning, 128 buckets/rel)
//    -> per-bucket LDS degree histogram -> scan -> per-bucket LDS counting
//    sort with streaming csr writes. No random global stores/atomics anywhere.
//    (R3 lesson: 448 concurrent ~100KB random-write windows = 44.8MB active
//    footprint > 32MB aggregate L2 -> 16x write amplification. LDS staging
//    makes the csr store stream coalesced at the instruction level.)
//  * Per relation r: gather_mean (CSR, 8-wide unroll, uint2 loads for 512B
//    rows) -> GEMM accumulating hacc += (1/7) * mean_r @ Wneigh[r].
//  * Self term: one GEMM per layer with pre-summed sum_r Wself[r].
//  * bf16 MFMA 16x16x32, 128x128 tiles, fp32 accumulate.
// Workspace ~259.6 MB (bucket pairs buffer aliases h1b/hacc region).
// ---------------------------------------------------------------------------

#define NN 100000
#define NREL 7
#define NE 1600000
#define NB 128           // buckets per relation
#define BCAP 14336       // slots per bucket (mean 12500, sigma~111 -> +16
#define BNODES 782       // ceil(100000/128)

using uint = unsigned int;
using ushort_t = unsigned short;
using bf16x8 = __attribute__((ext_vector_type(8))) __bf16;
using f32x4 = __attribute__((ext_vector_type(4))) float;

__device__ __forceinline__ ushort_t f32_to_bf16(float f) {
    uint u = __float_as_uint(f);
    u += 0x7fffu + ((u >> 16) & 1u);
    return (ushort_t)(u >> 16);
}
__device__ __forceinline__ float bf16lo(uint u) { return __uint_as_float(u << 16); }
__device__ __forceinline__ float bf16hi(uint u) { return __uint_as_float(u & 0xffff0000u); }

// ---------------- CSR build: pass 1 — LDS bucket binning -------------------
// Block: 256 threads x 16 edges = 4096 edge slots. Grid: (391, 7).
__global__ __launch_bounds__(256) void binpass_k(const int* __restrict__ edges,
                                                 int* __restrict__ bcnt,
                                                 uint2* __restrict__ bbuf) {
    __shared__ int cnt[NB];
    __shared__ int lofs[NB];
    __shared__ int gbase[NB];
    __shared__ int wtot[2];
    __shared__ int stotal;
    __shared__ uint2 stage[4096];       // 32 KB
    __shared__ unsigned char bb[4096];  // 4 KB
    int r = blockIdx.y;
    int t = threadIdx.x;
    if (t < NB) cnt[t] = 0;
    __syncthreads();
    int e0 = blockIdx.x * 4096;
    uint2 mypair[16];
    int myrb[16];  // (rank<<7)|b, or -1 invalid
    // Phase A: read edges (coalesced), LDS-rank per bucket.
#pragma unroll
    for (int i = 0; i < 16; ++i) {
        int e = e0 + i * 256 + t;
        if (e < NE) {
            int s = edges[(size_t)(2 * r) * NE + e];
            int d = edges[(size_t)(2 * r + 1) * NE + e];
            int b = d / BNODES;
            int rank = atomicAdd(&cnt[b], 1);
            myrb[i] = (rank << 7) | b;
            mypair[i] = make_uint2((uint)s, (uint)d);
        } else {
            myrb[i] = -1;
        }
    }
    __syncthreads();
    // Phase B: exclusive prefix over 128 buckets + global reservation.
    {
        int c = (t < NB) ? cnt[t] : 0;
        int lane = t & 63, wv = t >> 6;
        int x = c;
#pragma unroll
        for (int off = 1; off < 64; off <<= 1) {
            int y = __shfl_up(x, off);
            if (lane >= off) x += y;
        }
        if (t < NB && lane == 63) wtot[wv] = x;
        __syncthreads();
        if (t < NB) {
            int excl = x - c + (wv ? wtot[0] : 0);
            lofs[t] = excl;
            gbase[t] = atomicAdd(&bcnt[r * NB + t], c);
            if (t == NB - 1) stotal = excl + c;
        }
    }
    __syncthreads();
    // Phase C: stage pairs bucket-sorted in LDS.
#pragma unroll
    for (int i = 0; i < 16; ++i) {
        if (myrb[i] >= 0) {
            int b = myrb[i] & 127;
            int p = lofs[b] + (myrb[i] >> 7);
            stage[p] = mypair[i];
            bb[p] = (unsigned char)b;
        }
    }
    __syncthreads();
    // Phase D: write out bucket-contiguous runs (coalesced).
    int total = stotal;
    for (int p = t; p < total; p += 256) {
        int b = bb[p];
        uint2 pr = stage[p];
        int gpos = gbase[b] + (p - lofs[b]);
        if (gpos < BCAP)
            bbuf[((size_t)r * NB + b) * BCAP + gpos] = pr;
    }
}

// ---------------- CSR build: per-bucket LDS degree histogram ---------------
__global__ __launch_bounds__(1024) void deg_bucket_k(const uint2* __restrict__ bbuf,
                                                     const int* __restrict__ bcnt,
                                                     int* __restrict__ deg) {
    __shared__ int hist[BNODES];
    int rb = blockIdx.x;
    int r = rb >> 7, b = rb & 127;
    int node0 = b * BNODES;
    int nnodes = NN - node0 < BNODES ? NN - node0 : BNODES;
    int t = threadIdx.x;
    for (int i = t; i < nnodes; i += 1024) hist[i] = 0;
    __syncthreads();
    int cb = bcnt[rb];
    if (cb > BCAP) cb = BCAP;
    const uint2* src = bbuf + (size_t)rb * BCAP;
    for (int i = t; i < cb; i += 1024) {
        uint2 p = src[i];
        atomicAdd(&hist[(int)p.y - node0], 1);
    }
    __syncthreads();
    for (int i = t; i < nnodes; i += 1024) deg[r * NN + node0 + i] = hist[i];
}

// ---------------- CSR build: scan (deg -> rowptr) ----------------
__global__ void scan1_k(const int* __restrict__ deg, int* __restrict__ rowptr,
                        int* __restrict__ blk, int total) {
    __shared__ int wsum[4];
    int t = threadIdx.x;
    int base = blockIdx.x * 4096 + t * 16;
    int vals[16];
    int s = 0;
#pragma unroll
    for (int i = 0; i < 16; ++i) {
        int g = base + i;
        int v = (g < total) ? deg[g] : 0;
        vals[i] = s;
        s += v;
    }
    int lane = t & 63, w = t >> 6;
    int x = s;
    for (int off = 1; off < 64; off <<= 1) {
        int y = __shfl_up(x, off);
        if (lane >= off) x += y;
    }
    if (lane == 63) wsum[w] = x;
    __syncthreads();
    if (t == 0) {
        int a = 0;
#pragma unroll
        for (int k = 0; k < 4; ++k) { int b = wsum[k]; wsum[k] = a; a += b; }
        blk[blockIdx.x] = a;
    }
    __syncthreads();
    int excl = x - s + wsum[w];
#pragma unroll
    for (int i = 0; i < 16; ++i) {
        int g = base + i;
        if (g < total) rowptr[g] = excl + vals[i];
    }
}

__global__ void scan2_k(int* blk, int nb) {
    if (threadIdx.x == 0 && blockIdx.x == 0) {
        int a = 0;
        for (int i = 0; i < nb; ++i) { int b = blk[i]; blk[i] = a; a += b; }
    }
}

__global__ void scan3_k(int* __restrict__ rowptr, const int* __restrict__ blk, int total) {
    int t = threadIdx.x;
    int add = blk[blockIdx.x];
    int base = blockIdx.x * 4096 + t * 16;
#pragma unroll
    for (int i = 0; i < 16; ++i) {
        int g = base + i;
        if (g < total) rowptr[g] += add;
    }
}

// ---------------- CSR build: per-bucket LDS counting sort ------------------
// stage (57KB) + lcur (3KB) < 64KB LDS. csr writes are a coalesced stream.
__global__ __launch_bounds__(1024) void bucket_sort_k(const uint2* __restrict__ bbuf,
                                                      const int* __restrict__ bcnt,
                                                      const int* __restrict__ rowptr,
                                                      int* __restrict__ csr) {
    __shared__ int stage[BCAP];   // 57,344 B
    __shared__ int lcur[BNODES];  // 3,128 B
    int rb = blockIdx.x;
    int r = rb >> 7, b = rb & 127;
    int node0 = b * BNODES;
    int nnodes = NN - node0 < BNODES ? NN - node0 : BNODES;
    int t = threadIdx.x;
    int rowbase = rowptr[r * NN + node0];
    int endIdx = r * NN + node0 + nnodes;
    int rowend = (endIdx < NREL * NN) ? rowptr[endIdx] : (NREL * NE);
    int truen = rowend - rowbase;
    int nent = truen < BCAP ? truen : BCAP;
    for (int i = t; i < nent; i += 1024) stage[i] = 0;
    for (int i = t; i < nnodes; i += 1024) lcur[i] = 0;
    __syncthreads();
    int cb = bcnt[rb];
    if (cb > BCAP) cb = BCAP;
    const uint2* src = bbuf + (size_t)rb * BCAP;
    for (int i = t; i < cb; i += 1024) {
        uint2 p = src[i];
        int node = (int)p.y;
        int pos = rowptr[r * NN + node] - rowbase + atomicAdd(&lcur[node - node0], 1);
        if (pos < BCAP) stage[pos] = (int)p.x;
    }
    __syncthreads();
    for (int i = t; i < nent; i += 1024) csr[rowbase + i] = stage[i];
    for (int i = nent + t; i < truen; i += 1024) csr[rowbase + i] = 0;  // overflow guard
}

// ---------------- conversions / weight prep ----------------
__global__ void convert_x_k(const float* __restrict__ x, ushort_t* __restrict__ xb) {
    int idx = blockIdx.x * 256 + threadIdx.x;  // 100000*32 threads
    int n = idx >> 5;
    int c = idx & 31;
    float4 v = *(const float4*)(x + (size_t)n * 128 + c * 4);
    ushort4 o;
    o.x = f32_to_bf16(v.x); o.y = f32_to_bf16(v.y);
    o.z = f32_to_bf16(v.z); o.w = f32_to_bf16(v.w);
    *(ushort4*)(xb + (size_t)n * 128 + c * 4) = o;
}

__global__ void prep_B1_k(const float* __restrict__ Wself, const float* __restrict__ Wneigh,
                          const float* __restrict__ b, ushort_t* __restrict__ BsT,
                          ushort_t* __restrict__ BnT, float* __restrict__ bs) {
    int idx = blockIdx.x * 256 + threadIdx.x;  // 262400 threads
    if (idx < 32768) {
        int n = idx >> 7, k = idx & 127;
        float v = 0.f;
#pragma unroll
        for (int r = 0; r < 7; ++r) v += Wself[((size_t)r * 128 + k) * 256 + n];
        BsT[(size_t)n * 128 + k] = f32_to_bf16(v);
    } else if (idx < 262144) {
        int j = idx - 32768;
        int r = j >> 15;
        int rem = j & 32767;
        int n = rem >> 7, k = rem & 127;
        BnT[j] = f32_to_bf16(Wneigh[((size_t)r * 128 + k) * 256 + n]);
    } else {
        int i = idx - 262144;
        float s = 0.f;
#pragma unroll
        for (int r = 0; r < 7; ++r) s += b[r * 256 + i];
        bs[i] = s * (1.f / 7.f);
    }
}

__global__ void prep_B2_k(const float* __restrict__ Wself, const float* __restrict__ Wneigh,
                          const float* __restrict__ b, ushort_t* __restrict__ BsT,
                          ushort_t* __restrict__ BnT, float* __restrict__ bs) {
    int idx = blockIdx.x * 256 + threadIdx.x;
    if (idx >= 524544) return;
    if (idx < 65536) {
        int n = idx >> 8, k = idx & 255;
        float v = 0.f;
#pragma unroll
        for (int r = 0; r < 7; ++r) v += Wself[((size_t)r * 256 + k) * 256 + n];
        BsT[(size_t)n * 256 + k] = f32_to_bf16(v);
    } else if (idx < 524288) {
        int j = idx - 65536;
        int r = j >> 16;
        int rem = j & 65535;
        int n = rem >> 8, k = rem & 255;
        BnT[j] = f32_to_bf16(Wneigh[((size_t)r * 256 + k) * 256 + n]);
    } else {
        int i = idx - 524288;
        float s = 0.f;
#pragma unroll
        for (int r = 0; r < 7; ++r) s += b[r * 256 + i];
        bs[i] = s * (1.f / 7.f);
    }
}

__global__ void prep_cls_k(const float* __restrict__ Wc1, const float* __restrict__ bn_g,
                           const float* __restrict__ bn_b, const float* __restrict__ Wc2,
                           const float* __restrict__ bc2, ushort_t* __restrict__ Wc1T,
                           float* __restrict__ W2p, float* __restrict__ cp) {
    int idx = blockIdx.x * 256 + threadIdx.x;
    if (idx < 128 * 256) {
        int n = idx >> 8;
        int k = idx & 255;
        Wc1T[(size_t)n * 256 + k] = f32_to_bf16(Wc1[(size_t)k * 128 + n]);
    } else if (idx < 128 * 256 + 256) {
        int e = idx - 128 * 256;
        int d = e >> 1, j = e & 1;
        W2p[e] = bn_g[d] * rsqrtf(1.f + 1e-5f) * Wc2[d * 2 + j];
    } else if (idx < 128 * 256 + 256 + 2) {
        int j = idx - (128 * 256 + 256);
        float s = bc2[j];
        for (int d = 0; d < 128; ++d) s += bn_b[d] * Wc2[d * 2 + j];
        cp[j] = s;
    }
}

// ---------------- neighbor mean via CSR gather, 8-wide unroll --------------
// V=1: 256B rows, dword/lane. V=2: 512B rows, uint2/lane. One wave per node.
template <int V>
__global__ __launch_bounds__(256) void gather_mean_k(
    const ushort_t* __restrict__ T, const int* __restrict__ csr,
    const int* __restrict__ rowptr, const int* __restrict__ deg,
    ushort_t* __restrict__ Mout, int r) {
    int n = blockIdx.x * 4 + (threadIdx.x >> 6);
    if (n >= NN) return;
    int lane = threadIdx.x & 63;
    int pair = r * NN + n;
    int start = rowptr[pair];
    int cnt = deg[pair];
    float aLo[2][2] = {{0.f, 0.f}, {0.f, 0.f}};  // [component][parity]
    float aHi[2][2] = {{0.f, 0.f}, {0.f, 0.f}};
    int j = 0;
    if (V == 1) {
        const uint* Tu = (const uint*)T;
        for (; j + 8 <= cnt; j += 8) {
            int s[8];
#pragma unroll
            for (int q = 0; q < 8; ++q) s[q] = csr[start + j + q];
            uint u[8];
#pragma unroll
            for (int q = 0; q < 8; ++q) u[q] = Tu[(size_t)s[q] * 64 + lane];
#pragma unroll
            for (int q = 0; q < 8; ++q) {
                aLo[0][q & 1] += bf16lo(u[q]);
                aHi[0][q & 1] += bf16hi(u[q]);
            }
        }
        for (; j < cnt; ++j) {
            uint u = Tu[(size_t)csr[start + j] * 64 + lane];
            aLo[0][0] += bf16lo(u);
            aHi[0][0] += bf16hi(u);
        }
        float inv = 1.f / (float)(cnt > 1 ? cnt : 1);
        uint lo = f32_to_bf16((aLo[0][0] + aLo[0][1]) * inv);
        uint hi = f32_to_bf16((aHi[0][0] + aHi[0][1]) * inv);
        ((uint*)(Mout + (size_t)n * 128))[lane] = lo | (hi << 16);
    } else {
        const uint2* Tu = (const uint2*)T;
        for (; j + 8 <= cnt; j += 8) {
            int s[8];
#pragma unroll
            for (int q = 0; q < 8; ++q) s[q] = csr[start + j + q];
            uint2 u[8];
#pragma unroll
            for (int q = 0; q < 8; ++q) u[q] = Tu[(size_t)s[q] * 64 + lane];
#pragma unroll
            for (int q = 0; q < 8; ++q) {
                aLo[0][q & 1] += bf16lo(u[q].x);
                aHi[0][q & 1] += bf16hi(u[q].x);
                aLo[1][q & 1] += bf16lo(u[q].y);
                aHi[1][q & 1] += bf16hi(u[q].y);
            }
        }
        for (; j < cnt; ++j) {
            uint2 u = Tu[(size_t)csr[start + j] * 64 + lane];
            aLo[0][0] += bf16lo(u.x);
            aHi[0][0] += bf16hi(u.x);
            aLo[1][0] += bf16lo(u.y);
            aHi[1][0] += bf16hi(u.y);
        }
        float inv = 1.f / (float)(cnt > 1 ? cnt : 1);
        uint lox = f32_to_bf16((aLo[0][0] + aLo[0][1]) * inv);
        uint hix = f32_to_bf16((aHi[0][0] + aHi[0][1]) * inv);
        uint loy = f32_to_bf16((aLo[1][0] + aLo[1][1]) * inv);
        uint hiy = f32_to_bf16((aHi[1][0] + aHi[1][1]) * inv);
        ((uint2*)(Mout + (size_t)n * 256))[lane] =
            make_uint2(lox | (hix << 16), loy | (hiy << 16));
    }
}

// ---------------- bf16 MFMA GEMM ----------------
// A: M x K row-major bf16 (lda); BT: N x K row-major bf16; C: M x N f32.
// accumulate=0: C = alpha*(A@BT^T) + bias (opt relu). accumulate=1: C += alpha*(A@BT^T).
__global__ __launch_bounds__(256) void gemm_bf16(
    const ushort_t* __restrict__ A, int lda, const ushort_t* __restrict__ BT,
    float* __restrict__ C, int M, int N, int K, float alpha,
    const float* __restrict__ bias, int relu, int accumulate) {
    __shared__ __align__(16) ushort_t lA[128 * 40];
    __shared__ __align__(16) ushort_t lB[128 * 40];
    int t = threadIdx.x;
    int gr0 = blockIdx.x * 128;
    int gc0 = blockIdx.y * 128;
    int w = t >> 6, lane = t & 63;
    int wr = w >> 1, wc = w & 1;
    int lm = lane & 15, quad = lane >> 4;
    f32x4 acc[4][4];
#pragma unroll
    for (int i = 0; i < 4; ++i)
#pragma unroll
        for (int j = 0; j < 4; ++j) acc[i][j] = (f32x4){0.f, 0.f, 0.f, 0.f};

    for (int kk = 0; kk < K; kk += 32) {
        __syncthreads();
#pragma unroll
        for (int p = 0; p < 2; ++p) {
            int idx = p * 256 + t;
            int row = idx >> 2;
            int slot = idx & 3;
            uint4 av = make_uint4(0, 0, 0, 0);
            if (gr0 + row < M)
                av = *(const uint4*)(A + (size_t)(gr0 + row) * lda + kk + slot * 8);
            *(uint4*)(lA + row * 40 + slot * 8) = av;
            uint4 bv = make_uint4(0, 0, 0, 0);
            if (gc0 + row < N)
                bv = *(const uint4*)(BT + (size_t)(gc0 + row) * K + kk + slot * 8);
            *(uint4*)(lB + row * 40 + slot * 8) = bv;
        }
        __syncthreads();
        bf16x8 af[4], bfr[4];
#pragma unroll
        for (int f = 0; f < 4; ++f) {
            af[f] = *(const bf16x8*)(lA + (wr * 64 + f * 16 + lm) * 40 + quad * 8);
            bfr[f] = *(const bf16x8*)(lB + (wc * 64 + f * 16 + lm) * 40 + quad * 8);
        }
#pragma unroll
        for (int fr = 0; fr < 4; ++fr)
#pragma unroll
            for (int fc = 0; fc < 4; ++fc)
                acc[fr][fc] = __builtin_amdgcn_mfma_f32_16x16x32_bf16(
                    af[fr], bfr[fc], acc[fr][fc], 0, 0, 0);
    }
#pragma unroll
    for (int fr = 0; fr < 4; ++fr) {
#pragma unroll
        for (int fc = 0; fc < 4; ++fc) {
#pragma unroll
            for (int i = 0; i < 4; ++i) {
                int row = wr * 64 + fr * 16 + quad * 4 + i;
                int col = wc * 64 + fc * 16 + lm;
                int gr = gr0 + row;
                int gc = gc0 + col;
                if (gr < M) {
                    size_t o = (size_t)gr * N + gc;
                    float v = acc[fr][fc][i] * alpha;
                    if (accumulate) v += C[o];
                    else v += (bias ? bias[gc] : 0.f);
                    if (relu) v = fmaxf(v, 0.f);
                    C[o] = v;
                }
            }
        }
    }
}

// ---------------- LayerNorm + ReLU -> bf16 (row = 256) ----------------
__global__ __launch_bounds__(256) void ln_relu_k(
    const float* __restrict__ h, const float* __restrict__ g,
    const float* __restrict__ b, ushort_t* __restrict__ out) {
    int n = blockIdx.x * 4 + (threadIdx.x >> 6);
    if (n >= NN) return;
    int lane = threadIdx.x & 63;
    const float* row = h + (size_t)n * 256;
    float4 v = *(const float4*)(row + lane * 4);
    float s = v.x + v.y + v.z + v.w;
    float q = v.x * v.x + v.y * v.y + v.z * v.z + v.w * v.w;
#pragma unroll
    for (int m = 1; m < 64; m <<= 1) {
        s += __shfl_xor(s, m);
        q += __shfl_xor(q, m);
    }
    float mean = s * (1.f / 256.f);
    float var = q * (1.f / 256.f) - mean * mean;
    float rs = rsqrtf(var + 1e-5f);
    float4 gv = *(const float4*)(g + lane * 4);
    float4 bv = *(const float4*)(b + lane * 4);
    float y0 = fmaxf((v.x - mean) * rs * gv.x + bv.x, 0.f);
    float y1 = fmaxf((v.y - mean) * rs * gv.y + bv.y, 0.f);
    float y2 = fmaxf((v.z - mean) * rs * gv.z + bv.z, 0.f);
    float y3 = fmaxf((v.w - mean) * rs * gv.w + bv.w, 0.f);
    uint2 o;
    o.x = (uint)f32_to_bf16(y0) | ((uint)f32_to_bf16(y1) << 16);
    o.y = (uint)f32_to_bf16(y2) | ((uint)f32_to_bf16(y3) << 16);
    *(uint2*)(out + (size_t)n * 256 + lane * 4) = o;
}

// ---------------- final 128 -> 2 with folded BN ----------------
__global__ __launch_bounds__(256) void final_k(const float* __restrict__ z1,
                                               const float* __restrict__ W2p,
                                               const float* __restrict__ cp,
                                               float* __restrict__ out) {
    int n = blockIdx.x * 4 + (threadIdx.x >> 6);
    if (n >= NN) return;
    int lane = threadIdx.x & 63;
    const float* zr = z1 + (size_t)n * 128;
    float z0 = zr[lane], z1v = zr[lane + 64];
    float a0 = z0 * W2p[lane * 2 + 0] + z1v * W2p[(lane + 64) * 2 + 0];
    float a1 = z0 * W2p[lane * 2 + 1] + z1v * W2p[(lane + 64) * 2 + 1];
#pragma unroll
    for (int m = 1; m < 64; m <<= 1) {
        a0 += __shfl_xor(a0, m);
        a1 += __shfl_xor(a1, m);
    }
    if (lane == 0) {
        out[(size_t)n * 2 + 0] = a0 + cp[0];
        out[(size_t)n * 2 + 1] = a1 + cp[1];
    }
}

// ---------------- workspace layout (~259.6 MB, offsets 256B-aligned) --------
constexpr size_t O_DEG  = 0;             // 7*100000*4 = 2,800,000 (pad 2,800,128)
constexpr size_t O_CUR  = 2800128;       // (unused, kept for layout stability)
constexpr size_t O_ROW  = 5600256;
constexpr size_t O_BLK  = 8400384;       // 171*4
constexpr size_t O_CSR  = 8401408;       // 11.2M*4 = 44,800,000
constexpr size_t O_B1ST = 53201408;      // 256*128*2
constexpr size_t O_B1NT = 53266944;      // 7*256*128*2
constexpr size_t O_B2ST = 53725696;      // 256*256*2
constexpr size_t O_B2NT = 53856768;      // 7*256*256*2
constexpr size_t O_WC1T = 54774272;      // 128*256*2
constexpr size_t O_W2P  = 54839808;
constexpr size_t O_CP   = 54840832;
constexpr size_t O_B1S  = 54841088;
constexpr size_t O_B2S  = 54842112;
constexpr size_t O_X    = 54843136;      // x_bf16 100k*128*2 = 25,600,000
constexpr size_t O_M1   = 80443136;      // mean1 100k*128*2 = 25,600,000
constexpr size_t O_H1B  = 106043136;     // h1b 100k*256*2 = 51,200,000
constexpr size_t O_HACC = 157243136;     // hacc 100k*256*4 = 102,400,000
// bucket-pass scratch (CSR-build lifetime only, before h1b/hacc live):
constexpr size_t O_BCNT = O_H1B;                   // 7*128*4 (pad 4096)
constexpr size_t O_BBUF = O_H1B + 4096;            // 7*128*14336*8 = 102,760,448
constexpr size_t WS_REQUIRED = 259647232;

extern "C" void kernel_launch(void* const* d_in, const int* in_sizes, int n_in,
                              void* d_out, int out_size, void* d_ws, size_t ws_size,
                              hipStream_t stream) {
    (void)in_sizes; (void)n_in;
    const float* features = (const float*)d_in[0];
    const int* edges = (const int*)d_in[1];
    const float* Wself1 = (const float*)d_in[2];
    const float* Wneigh1 = (const float*)d_in[3];
    const float* b1 = (const float*)d_in[4];
    const float* Wself2 = (const float*)d_in[5];
    const float* Wneigh2 = (const float*)d_in[6];
    const float* b2 = (const float*)d_in[7];
    const float* ln_g = (const float*)d_in[8];
    const float* ln_b = (const float*)d_in[9];
    const float* Wc1 = (const float*)d_in[10];
    const float* bc1 = (const float*)d_in[11];
    const float* bn_g = (const float*)d_in[12];
    const float* bn_b = (const float*)d_in[13];
    const float* Wc2 = (const float*)d_in[14];
    const float* bc2 = (const float*)d_in[15];
    float* out = (float*)d_out;
    char* ws = (char*)d_ws;

    if (ws_size < WS_REQUIRED) {
        hipMemsetAsync(d_out, 0, (size_t)out_size * 4, stream);
        return;
    }

    int* deg = (int*)(ws + O_DEG);
    int* rowptr = (int*)(ws + O_ROW);
    int* blk = (int*)(ws + O_BLK);
    int* csr = (int*)(ws + O_CSR);
    ushort_t* B1sT = (ushort_t*)(ws + O_B1ST);
    ushort_t* B1nT = (ushort_t*)(ws + O_B1NT);
    ushort_t* B2sT = (ushort_t*)(ws + O_B2ST);
    ushort_t* B2nT = (ushort_t*)(ws + O_B2NT);
    ushort_t* Wc1T = (ushort_t*)(ws + O_WC1T);
    float* W2p = (float*)(ws + O_W2P);
    float* cp = (float*)(ws + O_CP);
    float* b1s = (float*)(ws + O_B1S);
    float* b2s = (float*)(ws + O_B2S);
    ushort_t* xb = (ushort_t*)(ws + O_X);
    ushort_t* mean1 = (ushort_t*)(ws + O_M1);
    ushort_t* mean2 = (ushort_t*)(ws + O_X);   // alias: x & mean1 dead in layer 2
    ushort_t* h2b = (ushort_t*)(ws + O_X);     // alias: mean2 dead after layer 2
    ushort_t* h1b = (ushort_t*)(ws + O_H1B);
    float* hacc = (float*)(ws + O_HACC);
    float* z1 = (float*)(ws + O_HACC);         // alias: hacc dead after LN2
    int* bcnt = (int*)(ws + O_BCNT);
    uint2* bbuf = (uint2*)(ws + O_BBUF);

    // zero bucket counters only (deg is fully overwritten by deg_bucket_k)
    hipMemsetAsync(ws + O_BCNT, 0, 4096, stream);

    // CSR build (shared by both layers) — all global traffic coalesced
    binpass_k<<<dim3(391, 7, 1), 256, 0, stream>>>(edges, bcnt, bbuf);
    deg_bucket_k<<<896, 1024, 0, stream>>>(bbuf, bcnt, deg);
    scan1_k<<<171, 256, 0, stream>>>(deg, rowptr, blk, NREL * NN);
    scan2_k<<<1, 64, 0, stream>>>(blk, 171);
    scan3_k<<<171, 256, 0, stream>>>(rowptr, blk, NREL * NN);
    bucket_sort_k<<<896, 1024, 0, stream>>>(bbuf, bcnt, rowptr, csr);

    // weight prep + x -> bf16
    convert_x_k<<<12500, 256, 0, stream>>>(features, xb);
    prep_B1_k<<<1025, 256, 0, stream>>>(Wself1, Wneigh1, b1, B1sT, B1nT, b1s);
    prep_B2_k<<<2050, 256, 0, stream>>>(Wself2, Wneigh2, b2, B2sT, B2nT, b2s);
    prep_cls_k<<<130, 256, 0, stream>>>(Wc1, bn_g, bn_b, Wc2, bc2, Wc1T, W2p, cp);

    // ---- layer 1: hacc = (1/7)[x@sumWself1 + sum_r mean_r@Wneigh1_r] + b1s
    gemm_bf16<<<dim3(782, 2, 1), 256, 0, stream>>>(xb, 128, B1sT, hacc,
                                                   NN, 256, 128, 1.f / 7.f, b1s, 0, 0);
    for (int r = 0; r < NREL; ++r) {
        gather_mean_k<1><<<25000, 256, 0, stream>>>(xb, csr, rowptr, deg, mean1, r);
        gemm_bf16<<<dim3(782, 2, 1), 256, 0, stream>>>(mean1, 128, B1nT + (size_t)r * 32768,
                                                       hacc, NN, 256, 128, 1.f / 7.f,
                                                       nullptr, 0, 1);
    }
    ln_relu_k<<<25000, 256, 0, stream>>>(hacc, ln_g, ln_b, h1b);

    // ---- layer 2
    gemm_bf16<<<dim3(782, 2, 1), 256, 0, stream>>>(h1b, 256, B2sT, hacc,
                                                   NN, 256, 256, 1.f / 7.f, b2s, 0, 0);
    for (int r = 0; r < NREL; ++r) {
        gather_mean_k<2><<<25000, 256, 0, stream>>>(h1b, csr, rowptr, deg, mean2, r);
        gemm_bf16<<<dim3(782, 2, 1), 256, 0, stream>>>(mean2, 256, B2nT + (size_t)r * 65536,
                                                       hacc, NN, 256, 256, 1.f / 7.f,
                                                       nullptr, 0, 1);
    }
    ln_relu_k<<<25000, 256, 0, stream>>>(hacc, ln_g + 256, ln_b + 256, h2b);

    // ---- classifier
    gemm_bf16<<<dim3(782, 1, 1), 256, 0, stream>>>(h2b, 256, Wc1T, z1,
                                                   NN, 128, 256, 1.f, bc1, 1, 0);
    final_k<<<25000, 256, 0, stream>>>(z1, W2p, cp, out);
}

// Round 5
// 2606.530 us; speedup vs baseline: 1.8801x; 1.1780x over previous
//
#include <hip/hip_runtime.h>
#include <hip/hip_bf16.h>
#include <cstdint>

// ---------------------------------------------------------------------------
// HeteroGNN: 2-layer hetero-SAGE (7 rel, 1.6M edges) + classifier, 100k nodes.
// Design C4:
//  * CSR build fully coalesced (binpass -> per-bucket LDS histogram -> scan ->
//    per-bucket LDS counting sort). [R3/R4 verified]
//  * Relations merged pairwise: per layer 4 dual-A GEMMs (K=2D) with
//    K-concatenated B panels: G0=[self|r0], G1=[r1|r2], G2=[r3|r4], G3=[r5|r6].
//    Cuts accumulator C-passes 15 -> 7 per layer (~2 GB HBM saved).
//  * Layer-1 acc fp32; layer-2 acc bf16 (memory-forced; 3 RMW roundings,
//    ~0.7% rel err, within absmax budget).
//  * gather_mean: CSR, 8-wide unroll, one wave per node. [R4: near mem floor]
// Workspace 257.2 MB, heavy aliasing (verified-fit: 259.6 MB passed in R2).
// ---------------------------------------------------------------------------

#define NN 100000
#define NREL 7
#define NE 1600000
#define NB 128           // buckets per relation
#define BCAP 14336       // slots per bucket (mean 12500)
#define BNODES 782       // ceil(100000/128)

using uint = unsigned int;
using ushort_t = unsigned short;
using bf16x8 = __attribute__((ext_vector_type(8))) __bf16;
using f32x4 = __attribute__((ext_vector_type(4))) float;

__device__ __forceinline__ ushort_t f32_to_bf16(float f) {
    uint u = __float_as_uint(f);
    u += 0x7fffu + ((u >> 16) & 1u);
    return (ushort_t)(u >> 16);
}
__device__ __forceinline__ float bf16lo(uint u) { return __uint_as_float(u << 16); }
__device__ __forceinline__ float bf16hi(uint u) { return __uint_as_float(u & 0xffff0000u); }

// ---------------- CSR build: pass 1 — LDS bucket binning -------------------
__global__ __launch_bounds__(256) void binpass_k(const int* __restrict__ edges,
                                                 int* __restrict__ bcnt,
                                                 uint2* __restrict__ bbuf) {
    __shared__ int cnt[NB];
    __shared__ int lofs[NB];
    __shared__ int gbase[NB];
    __shared__ int wtot[2];
    __shared__ int stotal;
    __shared__ uint2 stage[4096];
    __shared__ unsigned char bb[4096];
    int r = blockIdx.y;
    int t = threadIdx.x;
    if (t < NB) cnt[t] = 0;
    __syncthreads();
    int e0 = blockIdx.x * 4096;
    uint2 mypair[16];
    int myrb[16];
#pragma unroll
    for (int i = 0; i < 16; ++i) {
        int e = e0 + i * 256 + t;
        if (e < NE) {
            int s = edges[(size_t)(2 * r) * NE + e];
            int d = edges[(size_t)(2 * r + 1) * NE + e];
            int b = d / BNODES;
            int rank = atomicAdd(&cnt[b], 1);
            myrb[i] = (rank << 7) | b;
            mypair[i] = make_uint2((uint)s, (uint)d);
        } else {
            myrb[i] = -1;
        }
    }
    __syncthreads();
    {
        int c = (t < NB) ? cnt[t] : 0;
        int lane = t & 63, wv = t >> 6;
        int x = c;
#pragma unroll
        for (int off = 1; off < 64; off <<= 1) {
            int y = __shfl_up(x, off);
            if (lane >= off) x += y;
        }
        if (t < NB && lane == 63) wtot[wv] = x;
        __syncthreads();
        if (t < NB) {
            int excl = x - c + (wv ? wtot[0] : 0);
            lofs[t] = excl;
            gbase[t] = atomicAdd(&bcnt[r * NB + t], c);
            if (t == NB - 1) stotal = excl + c;
        }
    }
    __syncthreads();
#pragma unroll
    for (int i = 0; i < 16; ++i) {
        if (myrb[i] >= 0) {
            int b = myrb[i] & 127;
            int p = lofs[b] + (myrb[i] >> 7);
            stage[p] = mypair[i];
            bb[p] = (unsigned char)b;
        }
    }
    __syncthreads();
    int total = stotal;
    for (int p = t; p < total; p += 256) {
        int b = bb[p];
        uint2 pr = stage[p];
        int gpos = gbase[b] + (p - lofs[b]);
        if (gpos < BCAP)
            bbuf[((size_t)r * NB + b) * BCAP + gpos] = pr;
    }
}

// ---------------- CSR build: per-bucket LDS degree histogram ---------------
__global__ __launch_bounds__(1024) void deg_bucket_k(const uint2* __restrict__ bbuf,
                                                     const int* __restrict__ bcnt,
                                                     int* __restrict__ deg) {
    __shared__ int hist[BNODES];
    int rb = blockIdx.x;
    int r = rb >> 7, b = rb & 127;
    int node0 = b * BNODES;
    int nnodes = NN - node0 < BNODES ? NN - node0 : BNODES;
    int t = threadIdx.x;
    for (int i = t; i < nnodes; i += 1024) hist[i] = 0;
    __syncthreads();
    int cb = bcnt[rb];
    if (cb > BCAP) cb = BCAP;
    const uint2* src = bbuf + (size_t)rb * BCAP;
    for (int i = t; i < cb; i += 1024) {
        uint2 p = src[i];
        atomicAdd(&hist[(int)p.y - node0], 1);
    }
    __syncthreads();
    for (int i = t; i < nnodes; i += 1024) deg[r * NN + node0 + i] = hist[i];
}

// ---------------- CSR build: scan (deg -> rowptr) ----------------
__global__ void scan1_k(const int* __restrict__ deg, int* __restrict__ rowptr,
                        int* __restrict__ blk, int total) {
    __shared__ int wsum[4];
    int t = threadIdx.x;
    int base = blockIdx.x * 4096 + t * 16;
    int vals[16];
    int s = 0;
#pragma unroll
    for (int i = 0; i < 16; ++i) {
        int g = base + i;
        int v = (g < total) ? deg[g] : 0;
        vals[i] = s;
        s += v;
    }
    int lane = t & 63, w = t >> 6;
    int x = s;
    for (int off = 1; off < 64; off <<= 1) {
        int y = __shfl_up(x, off);
        if (lane >= off) x += y;
    }
    if (lane == 63) wsum[w] = x;
    __syncthreads();
    if (t == 0) {
        int a = 0;
#pragma unroll
        for (int k = 0; k < 4; ++k) { int b = wsum[k]; wsum[k] = a; a += b; }
        blk[blockIdx.x] = a;
    }
    __syncthreads();
    int excl = x - s + wsum[w];
#pragma unroll
    for (int i = 0; i < 16; ++i) {
        int g = base + i;
        if (g < total) rowptr[g] = excl + vals[i];
    }
}

__global__ void scan2_k(int* blk, int nb) {
    if (threadIdx.x == 0 && blockIdx.x == 0) {
        int a = 0;
        for (int i = 0; i < nb; ++i) { int b = blk[i]; blk[i] = a; a += b; }
    }
}

__global__ void scan3_k(int* __restrict__ rowptr, const int* __restrict__ blk, int total) {
    int t = threadIdx.x;
    int add = blk[blockIdx.x];
    int base = blockIdx.x * 4096 + t * 16;
#pragma unroll
    for (int i = 0; i < 16; ++i) {
        int g = base + i;
        if (g < total) rowptr[g] += add;
    }
}

// ---------------- CSR build: per-bucket LDS counting sort ------------------
__global__ __launch_bounds__(1024) void bucket_sort_k(const uint2* __restrict__ bbuf,
                                                      const int* __restrict__ bcnt,
                                                      const int* __restrict__ rowptr,
                                                      int* __restrict__ csr) {
    __shared__ int stage[BCAP];
    __shared__ int lcur[BNODES];
    int rb = blockIdx.x;
    int r = rb >> 7, b = rb & 127;
    int node0 = b * BNODES;
    int nnodes = NN - node0 < BNODES ? NN - node0 : BNODES;
    int t = threadIdx.x;
    int rowbase = rowptr[r * NN + node0];
    int endIdx = r * NN + node0 + nnodes;
    int rowend = (endIdx < NREL * NN) ? rowptr[endIdx] : (NREL * NE);
    int truen = rowend - rowbase;
    int nent = truen < BCAP ? truen : BCAP;
    for (int i = t; i < nent; i += 1024) stage[i] = 0;
    for (int i = t; i < nnodes; i += 1024) lcur[i] = 0;
    __syncthreads();
    int cb = bcnt[rb];
    if (cb > BCAP) cb = BCAP;
    const uint2* src = bbuf + (size_t)rb * BCAP;
    for (int i = t; i < cb; i += 1024) {
        uint2 p = src[i];
        int node = (int)p.y;
        int pos = rowptr[r * NN + node] - rowbase + atomicAdd(&lcur[node - node0], 1);
        if (pos < BCAP) stage[pos] = (int)p.x;
    }
    __syncthreads();
    for (int i = t; i < nent; i += 1024) csr[rowbase + i] = stage[i];
    for (int i = nent + t; i < truen; i += 1024) csr[rowbase + i] = 0;
}

// ---------------- conversions / weight prep ----------------
__global__ void convert_x_k(const float* __restrict__ x, ushort_t* __restrict__ xb) {
    int idx = blockIdx.x * 256 + threadIdx.x;
    int n = idx >> 5;
    int c = idx & 31;
    float4 v = *(const float4*)(x + (size_t)n * 128 + c * 4);
    ushort4 o;
    o.x = f32_to_bf16(v.x); o.y = f32_to_bf16(v.y);
    o.z = f32_to_bf16(v.z); o.w = f32_to_bf16(v.w);
    *(ushort4*)(xb + (size_t)n * 128 + c * 4) = o;
}

// B1cat: 4 panels of N=256 x K=256. Panel g: k<128 -> (g==0 ? sum Wself1 :
// Wneigh1[2g-1]); k>=128 -> Wneigh1[g==0 ? 0 : 2g]. Plus b1s = mean bias.
__global__ void prep_B1cat_k(const float* __restrict__ Wself, const float* __restrict__ Wneigh,
                             const float* __restrict__ b, ushort_t* __restrict__ Bcat,
                             float* __restrict__ bs) {
    int idx = blockIdx.x * 256 + threadIdx.x;  // 262144 + 256
    if (idx < 262144) {
        int g = idx >> 16;
        int rem = idx & 65535;
        int n = rem >> 8, k = rem & 255;
        float v;
        if (g == 0 && k < 128) {
            v = 0.f;
#pragma unroll
            for (int r = 0; r < 7; ++r) v += Wself[((size_t)r * 128 + k) * 256 + n];
        } else {
            int k2 = k & 127;
            int rel = (g == 0) ? 0 : (2 * g - 1 + (k >> 7));
            v = Wneigh[((size_t)rel * 128 + k2) * 256 + n];
        }
        Bcat[(size_t)g * 65536 + n * 256 + k] = f32_to_bf16(v);
    } else if (idx < 262400) {
        int i = idx - 262144;
        float s = 0.f;
#pragma unroll
        for (int r = 0; r < 7; ++r) s += b[r * 256 + i];
        bs[i] = s * (1.f / 7.f);
    }
}

// B2cat: 4 panels of N=256 x K=512 (same relation mapping, D=256).
__global__ void prep_B2cat_k(const float* __restrict__ Wself, const float* __restrict__ Wneigh,
                             const float* __restrict__ b, ushort_t* __restrict__ Bcat,
                             float* __restrict__ bs) {
    int idx = blockIdx.x * 256 + threadIdx.x;  // 524288 + 256
    if (idx < 524288) {
        int g = idx >> 17;
        int rem = idx & 131071;
        int n = rem >> 9, k = rem & 511;
        float v;
        if (g == 0 && k < 256) {
            v = 0.f;
#pragma unroll
            for (int r = 0; r < 7; ++r) v += Wself[((size_t)r * 256 + k) * 256 + n];
        } else {
            int k2 = k & 255;
            int rel = (g == 0) ? 0 : (2 * g - 1 + (k >> 8));
            v = Wneigh[((size_t)rel * 256 + k2) * 256 + n];
        }
        Bcat[(size_t)g * 131072 + n * 512 + k] = f32_to_bf16(v);
    } else if (idx < 524544) {
        int i = idx - 524288;
        float s = 0.f;
#pragma unroll
        for (int r = 0; r < 7; ++r) s += b[r * 256 + i];
        bs[i] = s * (1.f / 7.f);
    }
}

__global__ void prep_cls_k(const float* __restrict__ Wc1, const float* __restrict__ bn_g,
                           const float* __restrict__ bn_b, const float* __restrict__ Wc2,
                           const float* __restrict__ bc2, ushort_t* __restrict__ Wc1T,
                           float* __restrict__ W2p, float* __restrict__ cp) {
    int idx = blockIdx.x * 256 + threadIdx.x;
    if (idx < 128 * 256) {
        int n = idx >> 8;
        int k = idx & 255;
        Wc1T[(size_t)n * 256 + k] = f32_to_bf16(Wc1[(size_t)k * 128 + n]);
    } else if (idx < 128 * 256 + 256) {
        int e = idx - 128 * 256;
        int d = e >> 1, j = e & 1;
        W2p[e] = bn_g[d] * rsqrtf(1.f + 1e-5f) * Wc2[d * 2 + j];
    } else if (idx < 128 * 256 + 256 + 2) {
        int j = idx - (128 * 256 + 256);
        float s = bc2[j];
        for (int d = 0; d < 128; ++d) s += bn_b[d] * Wc2[d * 2 + j];
        cp[j] = s;
    }
}

// ---------------- neighbor mean via CSR gather, 8-wide unroll --------------
template <int V>
__global__ __launch_bounds__(256) void gather_mean_k(
    const ushort_t* __restrict__ T, const int* __restrict__ csr,
    const int* __restrict__ rowptr, const int* __restrict__ deg,
    ushort_t* __restrict__ Mout, int r) {
    int n = blockIdx.x * 4 + (threadIdx.x >> 6);
    if (n >= NN) return;
    int lane = threadIdx.x & 63;
    int pair = r * NN + n;
    int start = rowptr[pair];
    int cnt = deg[pair];
    float aLo[2][2] = {{0.f, 0.f}, {0.f, 0.f}};
    float aHi[2][2] = {{0.f, 0.f}, {0.f, 0.f}};
    int j = 0;
    if (V == 1) {
        const uint* Tu = (const uint*)T;
        for (; j + 8 <= cnt; j += 8) {
            int s[8];
#pragma unroll
            for (int q = 0; q < 8; ++q) s[q] = csr[start + j + q];
            uint u[8];
#pragma unroll
            for (int q = 0; q < 8; ++q) u[q] = Tu[(size_t)s[q] * 64 + lane];
#pragma unroll
            for (int q = 0; q < 8; ++q) {
                aLo[0][q & 1] += bf16lo(u[q]);
                aHi[0][q & 1] += bf16hi(u[q]);
            }
        }
        for (; j < cnt; ++j) {
            uint u = Tu[(size_t)csr[start + j] * 64 + lane];
            aLo[0][0] += bf16lo(u);
            aHi[0][0] += bf16hi(u);
        }
        float inv = 1.f / (float)(cnt > 1 ? cnt : 1);
        uint lo = f32_to_bf16((aLo[0][0] + aLo[0][1]) * inv);
        uint hi = f32_to_bf16((aHi[0][0] + aHi[0][1]) * inv);
        ((uint*)(Mout + (size_t)n * 128))[lane] = lo | (hi << 16);
    } else {
        const uint2* Tu = (const uint2*)T;
        for (; j + 8 <= cnt; j += 8) {
            int s[8];
#pragma unroll
            for (int q = 0; q < 8; ++q) s[q] = csr[start + j + q];
            uint2 u[8];
#pragma unroll
            for (int q = 0; q < 8; ++q) u[q] = Tu[(size_t)s[q] * 64 + lane];
#pragma unroll
            for (int q = 0; q < 8; ++q) {
                aLo[0][q & 1] += bf16lo(u[q].x);
                aHi[0][q & 1] += bf16hi(u[q].x);
                aLo[1][q & 1] += bf16lo(u[q].y);
                aHi[1][q & 1] += bf16hi(u[q].y);
            }
        }
        for (; j < cnt; ++j) {
            uint2 u = Tu[(size_t)csr[start + j] * 64 + lane];
            aLo[0][0] += bf16lo(u.x);
            aHi[0][0] += bf16hi(u.x);
            aLo[1][0] += bf16lo(u.y);
            aHi[1][0] += bf16hi(u.y);
        }
        float inv = 1.f / (float)(cnt > 1 ? cnt : 1);
        uint lox = f32_to_bf16((aLo[0][0] + aLo[0][1]) * inv);
        uint hix = f32_to_bf16((aHi[0][0] + aHi[0][1]) * inv);
        uint loy = f32_to_bf16((aLo[1][0] + aLo[1][1]) * inv);
        uint hiy = f32_to_bf16((aHi[1][0] + aHi[1][1]) * inv);
        ((uint2*)(Mout + (size_t)n * 256))[lane] =
            make_uint2(lox | (hix << 16), loy | (hiy << 16));
    }
}

// ---------------- dual-A bf16 MFMA GEMM ----------------
// A = [A0 | A1] along K (split at Ksplit), both M x Ksplit row-major (lda).
// BT: N x K row-major bf16. C: M x N.
// mode 0: Cf32 = a*acc+bias    1: Cf32 += a*acc
//      2: Cbf16 = a*acc+bias   3: Cbf16 += a*acc
//      4: Cf32 = relu(a*acc+bias)
__global__ __launch_bounds__(256) void gemm_dual(
    const ushort_t* __restrict__ A0, const ushort_t* __restrict__ A1,
    int lda, int Ksplit, const ushort_t* __restrict__ BT, void* __restrict__ Cv,
    int M, int N, int K, float alpha, const float* __restrict__ bias, int mode) {
    __shared__ __align__(16) ushort_t lA[128 * 40];
    __shared__ __align__(16) ushort_t lB[128 * 40];
    int t = threadIdx.x;
    int gr0 = blockIdx.x * 128;
    int gc0 = blockIdx.y * 128;
    int w = t >> 6, lane = t & 63;
    int wr = w >> 1, wc = w & 1;
    int lm = lane & 15, quad = lane >> 4;
    f32x4 acc[4][4];
#pragma unroll
    for (int i = 0; i < 4; ++i)
#pragma unroll
        for (int j = 0; j < 4; ++j) acc[i][j] = (f32x4){0.f, 0.f, 0.f, 0.f};

    for (int kk = 0; kk < K; kk += 32) {
        const ushort_t* Asrc = (kk < Ksplit) ? A0 : A1;
        int kloc = (kk < Ksplit) ? kk : (kk - Ksplit);
        __syncthreads();
#pragma unroll
        for (int p = 0; p < 2; ++p) {
            int idx = p * 256 + t;
            int row = idx >> 2;
            int slot = idx & 3;
            uint4 av = make_uint4(0, 0, 0, 0);
            if (gr0 + row < M)
                av = *(const uint4*)(Asrc + (size_t)(gr0 + row) * lda + kloc + slot * 8);
            *(uint4*)(lA + row * 40 + slot * 8) = av;
            uint4 bv = make_uint4(0, 0, 0, 0);
            if (gc0 + row < N)
                bv = *(const uint4*)(BT + (size_t)(gc0 + row) * K + kk + slot * 8);
            *(uint4*)(lB + row * 40 + slot * 8) = bv;
        }
        __syncthreads();
        bf16x8 af[4], bfr[4];
#pragma unroll
        for (int f = 0; f < 4; ++f) {
            af[f] = *(const bf16x8*)(lA + (wr * 64 + f * 16 + lm) * 40 + quad * 8);
            bfr[f] = *(const bf16x8*)(lB + (wc * 64 + f * 16 + lm) * 40 + quad * 8);
        }
#pragma unroll
        for (int fr = 0; fr < 4; ++fr)
#pragma unroll
            for (int fc = 0; fc < 4; ++fc)
                acc[fr][fc] = __builtin_amdgcn_mfma_f32_16x16x32_bf16(
                    af[fr], bfr[fc], acc[fr][fc], 0, 0, 0);
    }
    float* Cf = (float*)Cv;
    ushort_t* Cb = (ushort_t*)Cv;
#pragma unroll
    for (int fr = 0; fr < 4; ++fr) {
#pragma unroll
        for (int fc = 0; fc < 4; ++fc) {
#pragma unroll
            for (int i = 0; i < 4; ++i) {
                int row = wr * 64 + fr * 16 + quad * 4 + i;
                int col = wc * 64 + fc * 16 + lm;
                int gr = gr0 + row;
                int gc = gc0 + col;
                if (gr < M) {
                    size_t o = (size_t)gr * N + gc;
                    float v = acc[fr][fc][i] * alpha;
                    if (mode == 0 || mode == 2 || mode == 4)
                        v += bias ? bias[gc] : 0.f;
                    if (mode == 4) v = fmaxf(v, 0.f);
                    if (mode == 1) v += Cf[o];
                    if (mode == 3) v += bf16lo((uint)Cb[o] << 16) * 0.f +
                                        __uint_as_float((uint)Cb[o] << 16);
                    if (mode == 2 || mode == 3) Cb[o] = f32_to_bf16(v);
                    else Cf[o] = v;
                }
            }
        }
    }
}

// ---------------- LayerNorm + ReLU, f32 in -> bf16 out ----------------
__global__ __launch_bounds__(256) void ln_relu_k(
    const float* __restrict__ h, const float* __restrict__ g,
    const float* __restrict__ b, ushort_t* __restrict__ out) {
    int n = blockIdx.x * 4 + (threadIdx.x >> 6);
    if (n >= NN) return;
    int lane = threadIdx.x & 63;
    const float* row = h + (size_t)n * 256;
    float4 v = *(const float4*)(row + lane * 4);
    float s = v.x + v.y + v.z + v.w;
    float q = v.x * v.x + v.y * v.y + v.z * v.z + v.w * v.w;
#pragma unroll
    for (int m = 1; m < 64; m <<= 1) {
        s += __shfl_xor(s, m);
        q += __shfl_xor(q, m);
    }
    float mean = s * (1.f / 256.f);
    float var = q * (1.f / 256.f) - mean * mean;
    float rs = rsqrtf(var + 1e-5f);
    float4 gv = *(const float4*)(g + lane * 4);
    float4 bv = *(const float4*)(b + lane * 4);
    float y0 = fmaxf((v.x - mean) * rs * gv.x + bv.x, 0.f);
    float y1 = fmaxf((v.y - mean) * rs * gv.y + bv.y, 0.f);
    float y2 = fmaxf((v.z - mean) * rs * gv.z + bv.z, 0.f);
    float y3 = fmaxf((v.w - mean) * rs * gv.w + bv.w, 0.f);
    uint2 o;
    o.x = (uint)f32_to_bf16(y0) | ((uint)f32_to_bf16(y1) << 16);
    o.y = (uint)f32_to_bf16(y2) | ((uint)f32_to_bf16(y3) << 16);
    *(uint2*)(out + (size_t)n * 256 + lane * 4) = o;
}

// ---------------- LayerNorm + ReLU, bf16 in -> bf16 out ----------------
__global__ __launch_bounds__(256) void ln_relu_b_k(
    const ushort_t* __restrict__ h, const float* __restrict__ g,
    const float* __restrict__ b, ushort_t* __restrict__ out) {
    int n = blockIdx.x * 4 + (threadIdx.x >> 6);
    if (n >= NN) return;
    int lane = threadIdx.x & 63;
    uint2 u = ((const uint2*)(h + (size_t)n * 256))[lane];
    float v0 = bf16lo(u.x), v1 = bf16hi(u.x), v2 = bf16lo(u.y), v3 = bf16hi(u.y);
    float s = v0 + v1 + v2 + v3;
    float q = v0 * v0 + v1 * v1 + v2 * v2 + v3 * v3;
#pragma unroll
    for (int m = 1; m < 64; m <<= 1) {
        s += __shfl_xor(s, m);
        q += __shfl_xor(q, m);
    }
    float mean = s * (1.f / 256.f);
    float var = q * (1.f / 256.f) - mean * mean;
    float rs = rsqrtf(var + 1e-5f);
    float4 gv = *(const float4*)(g + lane * 4);
    float4 bv = *(const float4*)(b + lane * 4);
    float y0 = fmaxf((v0 - mean) * rs * gv.x + bv.x, 0.f);
    float y1 = fmaxf((v1 - mean) * rs * gv.y + bv.y, 0.f);
    float y2 = fmaxf((v2 - mean) * rs * gv.z + bv.z, 0.f);
    float y3 = fmaxf((v3 - mean) * rs * gv.w + bv.w, 0.f);
    uint2 o;
    o.x = (uint)f32_to_bf16(y0) | ((uint)f32_to_bf16(y1) << 16);
    o.y = (uint)f32_to_bf16(y2) | ((uint)f32_to_bf16(y3) << 16);
    *(uint2*)(out + (size_t)n * 256 + lane * 4) = o;
}

// ---------------- final 128 -> 2 with folded BN ----------------
__global__ __launch_bounds__(256) void final_k(const float* __restrict__ z1,
                                               const float* __restrict__ W2p,
                                               const float* __restrict__ cp,
                                               float* __restrict__ out) {
    int n = blockIdx.x * 4 + (threadIdx.x >> 6);
    if (n >= NN) return;
    int lane = threadIdx.x & 63;
    const float* zr = z1 + (size_t)n * 128;
    float z0 = zr[lane], z1v = zr[lane + 64];
    float a0 = z0 * W2p[lane * 2 + 0] + z1v * W2p[(lane + 64) * 2 + 0];
    float a1 = z0 * W2p[lane * 2 + 1] + z1v * W2p[(lane + 64) * 2 + 1];
#pragma unroll
    for (int m = 1; m < 64; m <<= 1) {
        a0 += __shfl_xor(a0, m);
        a1 += __shfl_xor(a1, m);
    }
    if (lane == 0) {
        out[(size_t)n * 2 + 0] = a0 + cp[0];
        out[(size_t)n * 2 + 1] = a1 + cp[1];
    }
}

// ---------------- workspace layout (257.2 MB, heavy aliasing) ---------------
constexpr size_t O_DEG   = 0;              // 2,800,000 -> pad 2,800,128
constexpr size_t O_ROW   = 2800128;        // 2,800,000 -> pad
constexpr size_t O_BLK   = 5600256;        // 684 -> pad 1024
constexpr size_t O_CSR   = 5601280;        // 44,800,000
constexpr size_t O_B1C   = 50401280;       // 4*256*256*2 = 524,288
constexpr size_t O_B2C   = 50925568;       // 4*256*512*2 = 1,048,576
constexpr size_t O_WC1T  = 51974144;       // 65,536
constexpr size_t O_W2P   = 52039680;       // 1024
constexpr size_t O_CP    = 52040704;       // 256
constexpr size_t O_B1S   = 52040960;       // 1024
constexpr size_t O_B2S   = 52041984;       // 1024
constexpr size_t O_XB    = 52043008;       // L1: xb 25,600,000
constexpr size_t O_MA1   = 77643008;       // L1: meanA 25,600,000
constexpr size_t O_MB1   = 103243008;      // L1: meanB 25,600,000
// CSR-build scratch (dead before convert_x):
constexpr size_t O_BCNT  = 52043008;       // 3,584 -> pad 4096
constexpr size_t O_BBUF  = 52047104;       // 102,760,448 -> end 154,807,552
constexpr size_t O_HACC1 = 154807552;      // L1 acc f32 102,400,000 -> end 257,207,552
// L2 aliases:
constexpr size_t O_H1B   = O_XB;           // 51,200,000 (over xb+meanA, dead)
constexpr size_t O_MA2   = O_MB1;          // 51,200,000
constexpr size_t O_MB2   = O_HACC1;        // 51,200,000 (over dead hacc1 lower)
constexpr size_t O_HACC2 = 206007552;      // bf16 51,200,000 (over dead hacc1 upper)
// classifier aliases:
constexpr size_t O_Z1    = O_MA2;          // f32 51,200,000 (mA2 dead)
constexpr size_t O_H2B   = O_MB2;          // bf16 51,200,000 (mB2 dead)
constexpr size_t WS_REQUIRED = 257207552;

extern "C" void kernel_launch(void* const* d_in, const int* in_sizes, int n_in,
                              void* d_out, int out_size, void* d_ws, size_t ws_size,
                              hipStream_t stream) {
    (void)in_sizes; (void)n_in;
    const float* features = (const float*)d_in[0];
    const int* edges = (const int*)d_in[1];
    const float* Wself1 = (const float*)d_in[2];
    const float* Wneigh1 = (const float*)d_in[3];
    const float* b1 = (const float*)d_in[4];
    const float* Wself2 = (const float*)d_in[5];
    const float* Wneigh2 = (const float*)d_in[6];
    const float* b2 = (const float*)d_in[7];
    const float* ln_g = (const float*)d_in[8];
    const float* ln_b = (const float*)d_in[9];
    const float* Wc1 = (const float*)d_in[10];
    const float* bc1 = (const float*)d_in[11];
    const float* bn_g = (const float*)d_in[12];
    const float* bn_b = (const float*)d_in[13];
    const float* Wc2 = (const float*)d_in[14];
    const float* bc2 = (const float*)d_in[15];
    float* out = (float*)d_out;
    char* ws = (char*)d_ws;

    if (ws_size < WS_REQUIRED) {
        hipMemsetAsync(d_out, 0, (size_t)out_size * 4, stream);
        return;
    }

    int* deg = (int*)(ws + O_DEG);
    int* rowptr = (int*)(ws + O_ROW);
    int* blk = (int*)(ws + O_BLK);
    int* csr = (int*)(ws + O_CSR);
    ushort_t* B1cat = (ushort_t*)(ws + O_B1C);
    ushort_t* B2cat = (ushort_t*)(ws + O_B2C);
    ushort_t* Wc1T = (ushort_t*)(ws + O_WC1T);
    float* W2p = (float*)(ws + O_W2P);
    float* cp = (float*)(ws + O_CP);
    float* b1s = (float*)(ws + O_B1S);
    float* b2s = (float*)(ws + O_B2S);
    ushort_t* xb = (ushort_t*)(ws + O_XB);
    ushort_t* mA1 = (ushort_t*)(ws + O_MA1);
    ushort_t* mB1 = (ushort_t*)(ws + O_MB1);
    float* hacc1 = (float*)(ws + O_HACC1);
    ushort_t* h1b = (ushort_t*)(ws + O_H1B);
    ushort_t* mA2 = (ushort_t*)(ws + O_MA2);
    ushort_t* mB2 = (ushort_t*)(ws + O_MB2);
    ushort_t* hacc2 = (ushort_t*)(ws + O_HACC2);
    float* z1 = (float*)(ws + O_Z1);
    ushort_t* h2b = (ushort_t*)(ws + O_H2B);
    int* bcnt = (int*)(ws + O_BCNT);
    uint2* bbuf = (uint2*)(ws + O_BBUF);

    hipMemsetAsync(ws + O_BCNT, 0, 4096, stream);

    // ---- CSR build (coalesced; bbuf scratch dead before convert_x) ----
    binpass_k<<<dim3(391, 7, 1), 256, 0, stream>>>(edges, bcnt, bbuf);
    deg_bucket_k<<<896, 1024, 0, stream>>>(bbuf, bcnt, deg);
    scan1_k<<<171, 256, 0, stream>>>(deg, rowptr, blk, NREL * NN);
    scan2_k<<<1, 64, 0, stream>>>(blk, 171);
    scan3_k<<<171, 256, 0, stream>>>(rowptr, blk, NREL * NN);
    bucket_sort_k<<<896, 1024, 0, stream>>>(bbuf, bcnt, rowptr, csr);

    // ---- weight prep + x -> bf16 (after CSR: xb aliases bbuf) ----
    convert_x_k<<<12500, 256, 0, stream>>>(features, xb);
    prep_B1cat_k<<<1025, 256, 0, stream>>>(Wself1, Wneigh1, b1, B1cat, b1s);
    prep_B2cat_k<<<2050, 256, 0, stream>>>(Wself2, Wneigh2, b2, B2cat, b2s);
    prep_cls_k<<<130, 256, 0, stream>>>(Wc1, bn_g, bn_b, Wc2, bc2, Wc1T, W2p, cp);

    // ---- layer 1: 4 paired GEMMs, acc f32 ----
    gather_mean_k<1><<<25000, 256, 0, stream>>>(xb, csr, rowptr, deg, mA1, 0);
    gemm_dual<<<dim3(782, 2, 1), 256, 0, stream>>>(xb, mA1, 128, 128, B1cat,
                                                   hacc1, NN, 256, 256, 1.f / 7.f, b1s, 0);
    for (int g = 1; g < 4; ++g) {
        gather_mean_k<1><<<25000, 256, 0, stream>>>(xb, csr, rowptr, deg, mA1, 2 * g - 1);
        gather_mean_k<1><<<25000, 256, 0, stream>>>(xb, csr, rowptr, deg, mB1, 2 * g);
        gemm_dual<<<dim3(782, 2, 1), 256, 0, stream>>>(mA1, mB1, 128, 128,
                                                       B1cat + (size_t)g * 65536,
                                                       hacc1, NN, 256, 256, 1.f / 7.f,
                                                       nullptr, 1);
    }
    ln_relu_k<<<25000, 256, 0, stream>>>(hacc1, ln_g, ln_b, h1b);

    // ---- layer 2: 4 paired GEMMs, acc bf16 ----
    gather_mean_k<2><<<25000, 256, 0, stream>>>(h1b, csr, rowptr, deg, mA2, 0);
    gemm_dual<<<dim3(782, 2, 1), 256, 0, stream>>>(h1b, mA2, 256, 256, B2cat,
                                                   hacc2, NN, 256, 512, 1.f / 7.f, b2s, 2);
    for (int g = 1; g < 4; ++g) {
        gather_mean_k<2><<<25000, 256, 0, stream>>>(h1b, csr, rowptr, deg, mA2, 2 * g - 1);
        gather_mean_k<2><<<25000, 256, 0, stream>>>(h1b, csr, rowptr, deg, mB2, 2 * g);
        gemm_dual<<<dim3(782, 2, 1), 256, 0, stream>>>(mA2, mB2, 256, 256,
                                                       B2cat + (size_t)g * 131072,
                                                       hacc2, NN, 256, 512, 1.f / 7.f,
                                                       nullptr, 3);
    }
    ln_relu_b_k<<<25000, 256, 0, stream>>>(hacc2, ln_g + 256, ln_b + 256, h2b);

    // ---- classifier ----
    gemm_dual<<<dim3(782, 1, 1), 256, 0, stream>>>(h2b, h2b, 256, 256, Wc1T,
                                                   z1, NN, 128, 256, 1.f, bc1, 4);
    final_k<<<25000, 256, 0, stream>>>(z1, W2p, cp, out);
}

// Round 6
// 2371.525 us; speedup vs baseline: 2.0664x; 1.0991x over previous
//
#include <hip/hip_runtime.h>
#include <hip/hip_bf16.h>
#include <cstdint>

// ---------------------------------------------------------------------------
// HeteroGNN: 2-layer hetero-SAGE (7 rel, 1.6M edges) + classifier, 100k nodes.
// Design C5:
//  * CSR build fully coalesced (binpass -> per-bucket LDS histogram -> scan ->
//    per-bucket LDS counting sort), SoA bucket buffer. [R4 verified]
//  * Pairwise-merged dual-A GEMMs per layer (4 GEMMs, K=2D). [R5 verified]
//  * GEMM rewritten m97-style: global_load_lds width=16 (no VGPR roundtrip),
//    unpadded 64B LDS rows (conflict-free b128 reads), BK=64 per barrier.
//    [R5 PMC: MfmaUtil 8%, Occ 24%, 6.4M LDS conflicts -> latency-bound]
//  * Both layer accumulators bf16 (halves C-RMW traffic).
//  * gather_mean: CSR, 8-wide unroll. [R4: ~7.1 TB/s effective, near ceiling]
// Workspace ~256.8 MB.
// ---------------------------------------------------------------------------

#define NN 100000
#define NREL 7
#define NE 1600000
#define NB 128           // buckets per relation
#define BCAP 14336       // slots per bucket (mean 12500)
#define BNODES 782       // ceil(100000/128)

using uint = unsigned int;
using ushort_t = unsigned short;
using bf16x8 = __attribute__((ext_vector_type(8))) __bf16;
using f32x4 = __attribute__((ext_vector_type(4))) float;

__device__ __forceinline__ ushort_t f32_to_bf16(float f) {
    uint u = __float_as_uint(f);
    u += 0x7fffu + ((u >> 16) & 1u);
    return (ushort_t)(u >> 16);
}
__device__ __forceinline__ float bf16lo(uint u) { return __uint_as_float(u << 16); }
__device__ __forceinline__ float bf16hi(uint u) { return __uint_as_float(u & 0xffff0000u); }

// async global->LDS, 16B per lane; LDS dest = wave-uniform base + lane*16
__device__ __forceinline__ void gload16(const ushort_t* g, ushort_t* l) {
    __builtin_amdgcn_global_load_lds(
        (const __attribute__((address_space(1))) uint*)g,
        (__attribute__((address_space(3))) uint*)l, 16, 0, 0);
}

// ---------------- CSR build: pass 1 — LDS bucket binning -------------------
__global__ __launch_bounds__(256) void binpass_k(const int* __restrict__ edges,
                                                 int* __restrict__ bcnt,
                                                 int* __restrict__ bsrc,
                                                 int* __restrict__ bdst) {
    __shared__ int cnt[NB];
    __shared__ int lofs[NB];
    __shared__ int gbase[NB];
    __shared__ int wtot[2];
    __shared__ int stotal;
    __shared__ uint2 stage[4096];
    __shared__ unsigned char bb[4096];
    int r = blockIdx.y;
    int t = threadIdx.x;
    if (t < NB) cnt[t] = 0;
    __syncthreads();
    int e0 = blockIdx.x * 4096;
    uint2 mypair[16];
    int myrb[16];
#pragma unroll
    for (int i = 0; i < 16; ++i) {
        int e = e0 + i * 256 + t;
        if (e < NE) {
            int s = edges[(size_t)(2 * r) * NE + e];
            int d = edges[(size_t)(2 * r + 1) * NE + e];
            int b = d / BNODES;
            int rank = atomicAdd(&cnt[b], 1);
            myrb[i] = (rank << 7) | b;
            mypair[i] = make_uint2((uint)s, (uint)d);
        } else {
            myrb[i] = -1;
        }
    }
    __syncthreads();
    {
        int c = (t < NB) ? cnt[t] : 0;
        int lane = t & 63, wv = t >> 6;
        int x = c;
#pragma unroll
        for (int off = 1; off < 64; off <<= 1) {
            int y = __shfl_up(x, off);
            if (lane >= off) x += y;
        }
        if (t < NB && lane == 63) wtot[wv] = x;
        __syncthreads();
        if (t < NB) {
            int excl = x - c + (wv ? wtot[0] : 0);
            lofs[t] = excl;
            gbase[t] = atomicAdd(&bcnt[r * NB + t], c);
            if (t == NB - 1) stotal = excl + c;
        }
    }
    __syncthreads();
#pragma unroll
    for (int i = 0; i < 16; ++i) {
        if (myrb[i] >= 0) {
            int b = myrb[i] & 127;
            int p = lofs[b] + (myrb[i] >> 7);
            stage[p] = mypair[i];
            bb[p] = (unsigned char)b;
        }
    }
    __syncthreads();
    int total = stotal;
    for (int p = t; p < total; p += 256) {
        int b = bb[p];
        uint2 pr = stage[p];
        int gpos = gbase[b] + (p - lofs[b]);
        if (gpos < BCAP) {
            size_t o = ((size_t)r * NB + b) * BCAP + gpos;
            bsrc[o] = (int)pr.x;
            bdst[o] = (int)pr.y;
        }
    }
}

// ---------------- CSR build: per-bucket LDS degree histogram ---------------
__global__ __launch_bounds__(1024) void deg_bucket_k(const int* __restrict__ bdst,
                                                     const int* __restrict__ bcnt,
                                                     int* __restrict__ deg) {
    __shared__ int hist[BNODES];
    int rb = blockIdx.x;
    int r = rb >> 7, b = rb & 127;
    int node0 = b * BNODES;
    int nnodes = NN - node0 < BNODES ? NN - node0 : BNODES;
    int t = threadIdx.x;
    for (int i = t; i < nnodes; i += 1024) hist[i] = 0;
    __syncthreads();
    int cb = bcnt[rb];
    if (cb > BCAP) cb = BCAP;
    const int* src = bdst + (size_t)rb * BCAP;
    for (int i = t; i < cb; i += 1024) {
        atomicAdd(&hist[src[i] - node0], 1);
    }
    __syncthreads();
    for (int i = t; i < nnodes; i += 1024) deg[r * NN + node0 + i] = hist[i];
}

// ---------------- CSR build: scan (deg -> rowptr) ----------------
__global__ void scan1_k(const int* __restrict__ deg, int* __restrict__ rowptr,
                        int* __restrict__ blk, int total) {
    __shared__ int wsum[4];
    int t = threadIdx.x;
    int base = blockIdx.x * 4096 + t * 16;
    int vals[16];
    int s = 0;
#pragma unroll
    for (int i = 0; i < 16; ++i) {
        int g = base + i;
        int v = (g < total) ? deg[g] : 0;
        vals[i] = s;
        s += v;
    }
    int lane = t & 63, w = t >> 6;
    int x = s;
    for (int off = 1; off < 64; off <<= 1) {
        int y = __shfl_up(x, off);
        if (lane >= off) x += y;
    }
    if (lane == 63) wsum[w] = x;
    __syncthreads();
    if (t == 0) {
        int a = 0;
#pragma unroll
        for (int k = 0; k < 4; ++k) { int b = wsum[k]; wsum[k] = a; a += b; }
        blk[blockIdx.x] = a;
    }
    __syncthreads();
    int excl = x - s + wsum[w];
#pragma unroll
    for (int i = 0; i < 16; ++i) {
        int g = base + i;
        if (g < total) rowptr[g] = excl + vals[i];
    }
}

__global__ void scan2_k(int* blk, int nb) {
    if (threadIdx.x == 0 && blockIdx.x == 0) {
        int a = 0;
        for (int i = 0; i < nb; ++i) { int b = blk[i]; blk[i] = a; a += b; }
    }
}

__global__ void scan3_k(int* __restrict__ rowptr, const int* __restrict__ blk, int total) {
    int t = threadIdx.x;
    int add = blk[blockIdx.x];
    int base = blockIdx.x * 4096 + t * 16;
#pragma unroll
    for (int i = 0; i < 16; ++i) {
        int g = base + i;
        if (g < total) rowptr[g] += add;
    }
}

// ---------------- CSR build: per-bucket LDS counting sort ------------------
__global__ __launch_bounds__(1024) void bucket_sort_k(const int* __restrict__ bsrc,
                                                      const int* __restrict__ bdst,
                                                      const int* __restrict__ bcnt,
                                                      const int* __restrict__ rowptr,
                                                      int* __restrict__ csr) {
    __shared__ int stage[BCAP];
    __shared__ int lcur[BNODES];
    int rb = blockIdx.x;
    int r = rb >> 7, b = rb & 127;
    int node0 = b * BNODES;
    int nnodes = NN - node0 < BNODES ? NN - node0 : BNODES;
    int t = threadIdx.x;
    int rowbase = rowptr[r * NN + node0];
    int endIdx = r * NN + node0 + nnodes;
    int rowend = (endIdx < NREL * NN) ? rowptr[endIdx] : (NREL * NE);
    int truen = rowend - rowbase;
    int nent = truen < BCAP ? truen : BCAP;
    for (int i = t; i < nent; i += 1024) stage[i] = 0;
    for (int i = t; i < nnodes; i += 1024) lcur[i] = 0;
    __syncthreads();
    int cb = bcnt[rb];
    if (cb > BCAP) cb = BCAP;
    for (int i = t; i < cb; i += 1024) {
        int node = bdst[(size_t)rb * BCAP + i];
        int sv = bsrc[(size_t)rb * BCAP + i];
        int pos = rowptr[r * NN + node] - rowbase + atomicAdd(&lcur[node - node0], 1);
        if (pos < BCAP) stage[pos] = sv;
    }
    __syncthreads();
    for (int i = t; i < nent; i += 1024) csr[rowbase + i] = stage[i];
    for (int i = nent + t; i < truen; i += 1024) csr[rowbase + i] = 0;
}

// ---------------- conversions / weight prep ----------------
__global__ void convert_x_k(const float* __restrict__ x, ushort_t* __restrict__ xb) {
    int idx = blockIdx.x * 256 + threadIdx.x;
    int n = idx >> 5;
    int c = idx & 31;
    float4 v = *(const float4*)(x + (size_t)n * 128 + c * 4);
    ushort4 o;
    o.x = f32_to_bf16(v.x); o.y = f32_to_bf16(v.y);
    o.z = f32_to_bf16(v.z); o.w = f32_to_bf16(v.w);
    *(ushort4*)(xb + (size_t)n * 128 + c * 4) = o;
}

__global__ void prep_B1cat_k(const float* __restrict__ Wself, const float* __restrict__ Wneigh,
                             const float* __restrict__ b, ushort_t* __restrict__ Bcat,
                             float* __restrict__ bs) {
    int idx = blockIdx.x * 256 + threadIdx.x;  // 262144 + 256
    if (idx < 262144) {
        int g = idx >> 16;
        int rem = idx & 65535;
        int n = rem >> 8, k = rem & 255;
        float v;
        if (g == 0 && k < 128) {
            v = 0.f;
#pragma unroll
            for (int r = 0; r < 7; ++r) v += Wself[((size_t)r * 128 + k) * 256 + n];
        } else {
            int k2 = k & 127;
            int rel = (g == 0) ? 0 : (2 * g - 1 + (k >> 7));
            v = Wneigh[((size_t)rel * 128 + k2) * 256 + n];
        }
        Bcat[(size_t)g * 65536 + n * 256 + k] = f32_to_bf16(v);
    } else if (idx < 262400) {
        int i = idx - 262144;
        float s = 0.f;
#pragma unroll
        for (int r = 0; r < 7; ++r) s += b[r * 256 + i];
        bs[i] = s * (1.f / 7.f);
    }
}

__global__ void prep_B2cat_k(const float* __restrict__ Wself, const float* __restrict__ Wneigh,
                             const float* __restrict__ b, ushort_t* __restrict__ Bcat,
                             float* __restrict__ bs) {
    int idx = blockIdx.x * 256 + threadIdx.x;  // 524288 + 256
    if (idx < 524288) {
        int g = idx >> 17;
        int rem = idx & 131071;
        int n = rem >> 9, k = rem & 511;
        float v;
        if (g == 0 && k < 256) {
            v = 0.f;
#pragma unroll
            for (int r = 0; r < 7; ++r) v += Wself[((size_t)r * 256 + k) * 256 + n];
        } else {
            int k2 = k & 255;
            int rel = (g == 0) ? 0 : (2 * g - 1 + (k >> 8));
            v = Wneigh[((size_t)rel * 256 + k2) * 256 + n];
        }
        Bcat[(size_t)g * 131072 + n * 512 + k] = f32_to_bf16(v);
    } else if (idx < 524544) {
        int i = idx - 524288;
        float s = 0.f;
#pragma unroll
        for (int r = 0; r < 7; ++r) s += b[r * 256 + i];
        bs[i] = s * (1.f / 7.f);
    }
}

__global__ void prep_cls_k(const float* __restrict__ Wc1, const float* __restrict__ bn_g,
                           const float* __restrict__ bn_b, const float* __restrict__ Wc2,
                           const float* __restrict__ bc2, ushort_t* __restrict__ Wc1T,
                           float* __restrict__ W2p, float* __restrict__ cp) {
    int idx = blockIdx.x * 256 + threadIdx.x;
    if (idx < 128 * 256) {
        int n = idx >> 8;
        int k = idx & 255;
        Wc1T[(size_t)n * 256 + k] = f32_to_bf16(Wc1[(size_t)k * 128 + n]);
    } else if (idx < 128 * 256 + 256) {
        int e = idx - 128 * 256;
        int d = e >> 1, j = e & 1;
        W2p[e] = bn_g[d] * rsqrtf(1.f + 1e-5f) * Wc2[d * 2 + j];
    } else if (idx < 128 * 256 + 256 + 2) {
        int j = idx - (128 * 256 + 256);
        float s = bc2[j];
        for (int d = 0; d < 128; ++d) s += bn_b[d] * Wc2[d * 2 + j];
        cp[j] = s;
    }
}

// ---------------- neighbor mean via CSR gather, 8-wide unroll --------------
template <int V>
__global__ __launch_bounds__(256) void gather_mean_k(
    const ushort_t* __restrict__ T, const int* __restrict__ csr,
    const int* __restrict__ rowptr, const int* __restrict__ deg,
    ushort_t* __restrict__ Mout, int r) {
    int n = blockIdx.x * 4 + (threadIdx.x >> 6);
    if (n >= NN) return;
    int lane = threadIdx.x & 63;
    int pair = r * NN + n;
    int start = rowptr[pair];
    int cnt = deg[pair];
    float aLo[2][2] = {{0.f, 0.f}, {0.f, 0.f}};
    float aHi[2][2] = {{0.f, 0.f}, {0.f, 0.f}};
    int j = 0;
    if (V == 1) {
        const uint* Tu = (const uint*)T;
        for (; j + 8 <= cnt; j += 8) {
            int s[8];
#pragma unroll
            for (int q = 0; q < 8; ++q) s[q] = csr[start + j + q];
            uint u[8];
#pragma unroll
            for (int q = 0; q < 8; ++q) u[q] = Tu[(size_t)s[q] * 64 + lane];
#pragma unroll
            for (int q = 0; q < 8; ++q) {
                aLo[0][q & 1] += bf16lo(u[q]);
                aHi[0][q & 1] += bf16hi(u[q]);
            }
        }
        for (; j < cnt; ++j) {
            uint u = Tu[(size_t)csr[start + j] * 64 + lane];
            aLo[0][0] += bf16lo(u);
            aHi[0][0] += bf16hi(u);
        }
        float inv = 1.f / (float)(cnt > 1 ? cnt : 1);
        uint lo = f32_to_bf16((aLo[0][0] + aLo[0][1]) * inv);
        uint hi = f32_to_bf16((aHi[0][0] + aHi[0][1]) * inv);
        ((uint*)(Mout + (size_t)n * 128))[lane] = lo | (hi << 16);
    } else {
        const uint2* Tu = (const uint2*)T;
        for (; j + 8 <= cnt; j += 8) {
            int s[8];
#pragma unroll
            for (int q = 0; q < 8; ++q) s[q] = csr[start + j + q];
            uint2 u[8];
#pragma unroll
            for (int q = 0; q < 8; ++q) u[q] = Tu[(size_t)s[q] * 64 + lane];
#pragma unroll
            for (int q = 0; q < 8; ++q) {
                aLo[0][q & 1] += bf16lo(u[q].x);
                aHi[0][q & 1] += bf16hi(u[q].x);
                aLo[1][q & 1] += bf16lo(u[q].y);
                aHi[1][q & 1] += bf16hi(u[q].y);
            }
        }
        for (; j < cnt; ++j) {
            uint2 u = Tu[(size_t)csr[start + j] * 64 + lane];
            aLo[0][0] += bf16lo(u.x);
            aHi[0][0] += bf16hi(u.x);
            aLo[1][0] += bf16lo(u.y);
            aHi[1][0] += bf16hi(u.y);
        }
        float inv = 1.f / (float)(cnt > 1 ? cnt : 1);
        uint lox = f32_to_bf16((aLo[0][0] + aLo[0][1]) * inv);
        uint hix = f32_to_bf16((aHi[0][0] + aHi[0][1]) * inv);
        uint loy = f32_to_bf16((aLo[1][0] + aLo[1][1]) * inv);
        uint hiy = f32_to_bf16((aHi[1][0] + aHi[1][1]) * inv);
        ((uint2*)(Mout + (size_t)n * 256))[lane] =
            make_uint2(lox | (hix << 16), loy | (hiy << 16));
    }
}

// ---------------- dual-A bf16 MFMA GEMM (m97-style staging) ----------------
// A = [A0 | A1] along K (split at Ksplit), both M x Ksplit row-major (lda).
// BT: N x K row-major bf16. C: M x N.
// mode 0: Cf32 = a*acc+bias    2: Cbf16 = a*acc+bias
//      3: Cbf16 += a*acc       4: Cf32 = relu(a*acc+bias)
// LDS: unpadded 64B rows (32 ushort) per 32-K sub-panel; BK=64 per barrier.
__global__ __launch_bounds__(256) void gemm_dual(
    const ushort_t* __restrict__ A0, const ushort_t* __restrict__ A1,
    int lda, int Ksplit, const ushort_t* __restrict__ BT, void* __restrict__ Cv,
    int M, int N, int K, float alpha, const float* __restrict__ bias, int mode) {
    __shared__ __align__(16) ushort_t lA[2 * 4096];  // 2 sub-panels of 128x32
    __shared__ __align__(16) ushort_t lB[2 * 4096];
    int t = threadIdx.x;
    int gr0 = blockIdx.x * 128;
    int gc0 = blockIdx.y * 128;
    int w = t >> 6, lane = t & 63;
    int wr = w >> 1, wc = w & 1;
    int lm = lane & 15, quad = lane >> 4;
    int srow = lane >> 2;            // staging: row within 16-row group
    int schunk = (lane & 3) * 8;     // staging: 8-ushort chunk within 32
    f32x4 acc[4][4];
#pragma unroll
    for (int i = 0; i < 4; ++i)
#pragma unroll
        for (int j = 0; j < 4; ++j) acc[i][j] = (f32x4){0.f, 0.f, 0.f, 0.f};

    for (int kk = 0; kk < K; kk += 64) {
        const ushort_t* Asrc = (kk < Ksplit) ? A0 : A1;
        int kloc = (kk < Ksplit) ? kk : (kk - Ksplit);
        __syncthreads();
#pragma unroll
        for (int s = 0; s < 2; ++s) {
#pragma unroll
            for (int j = 0; j < 2; ++j) {
                int rb = (j * 4 + w) * 16;        // wave-uniform row base
                int row = rb + srow;
                int gr = gr0 + row;
                if (gr < M)
                    gload16(Asrc + (size_t)gr * lda + kloc + s * 32 + schunk,
                            lA + s * 4096 + rb * 32);
                gload16(BT + (size_t)(gc0 + row) * K + kk + s * 32 + schunk,
                        lB + s * 4096 + rb * 32);
            }
        }
        __syncthreads();
#pragma unroll
        for (int s = 0; s < 2; ++s) {
            bf16x8 af[4], bfr[4];
#pragma unroll
            for (int f = 0; f < 4; ++f) {
                af[f] = *(const bf16x8*)(lA + s * 4096 + (wr * 64 + f * 16 + lm) * 32 + quad * 8);
                bfr[f] = *(const bf16x8*)(lB + s * 4096 + (wc * 64 + f * 16 + lm) * 32 + quad * 8);
            }
#pragma unroll
            for (int fr = 0; fr < 4; ++fr)
#pragma unroll
                for (int fc = 0; fc < 4; ++fc)
                    acc[fr][fc] = __builtin_amdgcn_mfma_f32_16x16x32_bf16(
                        af[fr], bfr[fc], acc[fr][fc], 0, 0, 0);
        }
    }
    float* Cf = (float*)Cv;
    ushort_t* Cb = (ushort_t*)Cv;
#pragma unroll
    for (int fr = 0; fr < 4; ++fr) {
#pragma unroll
        for (int fc = 0; fc < 4; ++fc) {
#pragma unroll
            for (int i = 0; i < 4; ++i) {
                int row = wr * 64 + fr * 16 + quad * 4 + i;
                int col = wc * 64 + fc * 16 + lm;
                int gr = gr0 + row;
                int gc = gc0 + col;
                if (gr < M) {
                    size_t o = (size_t)gr * N + gc;
                    float v = acc[fr][fc][i] * alpha;
                    if (mode == 0 || mode == 2 || mode == 4)
                        v += bias ? bias[gc] : 0.f;
                    if (mode == 4) v = fmaxf(v, 0.f);
                    if (mode == 3) v += __uint_as_float((uint)Cb[o] << 16);
                    if (mode == 2 || mode == 3) Cb[o] = f32_to_bf16(v);
                    else Cf[o] = v;
                }
            }
        }
    }
}

// ---------------- LayerNorm + ReLU, bf16 in -> bf16 out ----------------
__global__ __launch_bounds__(256) void ln_relu_b_k(
    const ushort_t* __restrict__ h, const float* __restrict__ g,
    const float* __restrict__ b, ushort_t* __restrict__ out) {
    int n = blockIdx.x * 4 + (threadIdx.x >> 6);
    if (n >= NN) return;
    int lane = threadIdx.x & 63;
    uint2 u = ((const uint2*)(h + (size_t)n * 256))[lane];
    float v0 = bf16lo(u.x), v1 = bf16hi(u.x), v2 = bf16lo(u.y), v3 = bf16hi(u.y);
    float s = v0 + v1 + v2 + v3;
    float q = v0 * v0 + v1 * v1 + v2 * v2 + v3 * v3;
#pragma unroll
    for (int m = 1; m < 64; m <<= 1) {
        s += __shfl_xor(s, m);
        q += __shfl_xor(q, m);
    }
    float mean = s * (1.f / 256.f);
    float var = q * (1.f / 256.f) - mean * mean;
    float rs = rsqrtf(var + 1e-5f);
    float4 gv = *(const float4*)(g + lane * 4);
    float4 bv = *(const float4*)(b + lane * 4);
    float y0 = fmaxf((v0 - mean) * rs * gv.x + bv.x, 0.f);
    float y1 = fmaxf((v1 - mean) * rs * gv.y + bv.y, 0.f);
    float y2 = fmaxf((v2 - mean) * rs * gv.z + bv.z, 0.f);
    float y3 = fmaxf((v3 - mean) * rs * gv.w + bv.w, 0.f);
    uint2 o;
    o.x = (uint)f32_to_bf16(y0) | ((uint)f32_to_bf16(y1) << 16);
    o.y = (uint)f32_to_bf16(y2) | ((uint)f32_to_bf16(y3) << 16);
    *(uint2*)(out + (size_t)n * 256 + lane * 4) = o;
}

// ---------------- final 128 -> 2 with folded BN ----------------
__global__ __launch_bounds__(256) void final_k(const float* __restrict__ z1,
                                               const float* __restrict__ W2p,
                                               const float* __restrict__ cp,
                                               float* __restrict__ out) {
    int n = blockIdx.x * 4 + (threadIdx.x >> 6);
    if (n >= NN) return;
    int lane = threadIdx.x & 63;
    const float* zr = z1 + (size_t)n * 128;
    float z0 = zr[lane], z1v = zr[lane + 64];
    float a0 = z0 * W2p[lane * 2 + 0] + z1v * W2p[(lane + 64) * 2 + 0];
    float a1 = z0 * W2p[lane * 2 + 1] + z1v * W2p[(lane + 64) * 2 + 1];
#pragma unroll
    for (int m = 1; m < 64; m <<= 1) {
        a0 += __shfl_xor(a0, m);
        a1 += __shfl_xor(a1, m);
    }
    if (lane == 0) {
        out[(size_t)n * 2 + 0] = a0 + cp[0];
        out[(size_t)n * 2 + 1] = a1 + cp[1];
    }
}

// ---------------- workspace layout (~256.8 MB) ------------------------------
constexpr size_t O_DEG   = 0;              // 2,800,000 -> pad 2,800,128
constexpr size_t O_ROW   = 2800128;
constexpr size_t O_BLK   = 5600256;        // pad 1024
constexpr size_t O_CSR   = 5601280;        // 44,800,000
constexpr size_t O_B1C   = 50401280;       // 524,288
constexpr size_t O_B2C   = 50925568;       // 1,048,576
constexpr size_t O_WC1T  = 51974144;       // 65,536
constexpr size_t O_W2P   = 52039680;       // 1024
constexpr size_t O_CP    = 52040704;       // 256
constexpr size_t O_B1S   = 52040960;       // 1024
constexpr size_t O_B2S   = 52041984;       // 1024
constexpr size_t O_XB    = 52043008;       // L1: xb bf16 25,600,000
constexpr size_t O_MA1   = 77643008;       // L1: meanA 25,600,000
constexpr size_t O_MB1   = 103243008;      // L1: meanB 25,600,000
constexpr size_t O_HACC1 = 128843008;      // L1 acc bf16 51,200,000 -> 180,043,008
// CSR-build scratch (dead before convert_x), SoA:
constexpr size_t O_BCNT  = 52043008;       // pad 4096
constexpr size_t O_BSRC  = 52047104;       // 51,380,224
constexpr size_t O_BDST  = 103427328;      // 51,380,224 -> 154,807,552
// L2 aliases:
constexpr size_t O_H1B   = O_XB;           // 51,200,000 (xb+mA1 dead)
constexpr size_t O_MA2   = 103243008;      // 51,200,000 (mB1+hacc1-lo dead after LN1)
constexpr size_t O_MB2   = 154443008;      // 51,200,000
constexpr size_t O_HACC2 = 205643008;      // bf16 51,200,000 -> 256,843,008
// classifier aliases:
constexpr size_t O_H2B   = O_XB;           // bf16 (h1b dead after L2)
constexpr size_t O_Z1    = O_MA2;          // f32 51,200,000 (mA2 dead)
constexpr size_t WS_REQUIRED = 256843008;

extern "C" void kernel_launch(void* const* d_in, const int* in_sizes, int n_in,
                              void* d_out, int out_size, void* d_ws, size_t ws_size,
                              hipStream_t stream) {
    (void)in_sizes; (void)n_in;
    const float* features = (const float*)d_in[0];
    const int* edges = (const int*)d_in[1];
    const float* Wself1 = (const float*)d_in[2];
    const float* Wneigh1 = (const float*)d_in[3];
    const float* b1 = (const float*)d_in[4];
    const float* Wself2 = (const float*)d_in[5];
    const float* Wneigh2 = (const float*)d_in[6];
    const float* b2 = (const float*)d_in[7];
    const float* ln_g = (const float*)d_in[8];
    const float* ln_b = (const float*)d_in[9];
    const float* Wc1 = (const float*)d_in[10];
    const float* bc1 = (const float*)d_in[11];
    const float* bn_g = (const float*)d_in[12];
    const float* bn_b = (const float*)d_in[13];
    const float* Wc2 = (const float*)d_in[14];
    const float* bc2 = (const float*)d_in[15];
    float* out = (float*)d_out;
    char* ws = (char*)d_ws;

    if (ws_size < WS_REQUIRED) {
        hipMemsetAsync(d_out, 0, (size_t)out_size * 4, stream);
        return;
    }

    int* deg = (int*)(ws + O_DEG);
    int* rowptr = (int*)(ws + O_ROW);
    int* blk = (int*)(ws + O_BLK);
    int* csr = (int*)(ws + O_CSR);
    ushort_t* B1cat = (ushort_t*)(ws + O_B1C);
    ushort_t* B2cat = (ushort_t*)(ws + O_B2C);
    ushort_t* Wc1T = (ushort_t*)(ws + O_WC1T);
    float* W2p = (float*)(ws + O_W2P);
    float* cp = (float*)(ws + O_CP);
    float* b1s = (float*)(ws + O_B1S);
    float* b2s = (float*)(ws + O_B2S);
    ushort_t* xb = (ushort_t*)(ws + O_XB);
    ushort_t* mA1 = (ushort_t*)(ws + O_MA1);
    ushort_t* mB1 = (ushort_t*)(ws + O_MB1);
    ushort_t* hacc1 = (ushort_t*)(ws + O_HACC1);
    ushort_t* h1b = (ushort_t*)(ws + O_H1B);
    ushort_t* mA2 = (ushort_t*)(ws + O_MA2);
    ushort_t* mB2 = (ushort_t*)(ws + O_MB2);
    ushort_t* hacc2 = (ushort_t*)(ws + O_HACC2);
    ushort_t* h2b = (ushort_t*)(ws + O_H2B);
    float* z1 = (float*)(ws + O_Z1);
    int* bcnt = (int*)(ws + O_BCNT);
    int* bsrc = (int*)(ws + O_BSRC);
    int* bdst = (int*)(ws + O_BDST);

    hipMemsetAsync(ws + O_BCNT, 0, 4096, stream);

    // ---- CSR build (coalesced; scratch dead before convert_x) ----
    binpass_k<<<dim3(391, 7, 1), 256, 0, stream>>>(edges, bcnt, bsrc, bdst);
    deg_bucket_k<<<896, 1024, 0, stream>>>(bdst, bcnt, deg);
    scan1_k<<<171, 256, 0, stream>>>(deg, rowptr, blk, NREL * NN);
    scan2_k<<<1, 64, 0, stream>>>(blk, 171);
    scan3_k<<<171, 256, 0, stream>>>(rowptr, blk, NREL * NN);
    bucket_sort_k<<<896, 1024, 0, stream>>>(bsrc, bdst, bcnt, rowptr, csr);

    // ---- weight prep + x -> bf16 ----
    convert_x_k<<<12500, 256, 0, stream>>>(features, xb);
    prep_B1cat_k<<<1025, 256, 0, stream>>>(Wself1, Wneigh1, b1, B1cat, b1s);
    prep_B2cat_k<<<2050, 256, 0, stream>>>(Wself2, Wneigh2, b2, B2cat, b2s);
    prep_cls_k<<<130, 256, 0, stream>>>(Wc1, bn_g, bn_b, Wc2, bc2, Wc1T, W2p, cp);

    // ---- layer 1: 4 paired GEMMs, acc bf16 ----
    gather_mean_k<1><<<25000, 256, 0, stream>>>(xb, csr, rowptr, deg, mA1, 0);
    gemm_dual<<<dim3(782, 2, 1), 256, 0, stream>>>(xb, mA1, 128, 128, B1cat,
                                                   hacc1, NN, 256, 256, 1.f / 7.f, b1s, 2);
    for (int g = 1; g < 4; ++g) {
        gather_mean_k<1><<<25000, 256, 0, stream>>>(xb, csr, rowptr, deg, mA1, 2 * g - 1);
        gather_mean_k<1><<<25000, 256, 0, stream>>>(xb, csr, rowptr, deg, mB1, 2 * g);
        gemm_dual<<<dim3(782, 2, 1), 256, 0, stream>>>(mA1, mB1, 128, 128,
                                                       B1cat + (size_t)g * 65536,
                                                       hacc1, NN, 256, 256, 1.f / 7.f,
                                                       nullptr, 3);
    }
    ln_relu_b_k<<<25000, 256, 0, stream>>>(hacc1, ln_g, ln_b, h1b);

    // ---- layer 2: 4 paired GEMMs, acc bf16 ----
    gather_mean_k<2><<<25000, 256, 0, stream>>>(h1b, csr, rowptr, deg, mA2, 0);
    gemm_dual<<<dim3(782, 2, 1), 256, 0, stream>>>(h1b, mA2, 256, 256, B2cat,
                                                   hacc2, NN, 256, 512, 1.f / 7.f, b2s, 2);
    for (int g = 1; g < 4; ++g) {
        gather_mean_k<2><<<25000, 256, 0, stream>>>(h1b, csr, rowptr, deg, mA2, 2 * g - 1);
        gather_mean_k<2><<<25000, 256, 0, stream>>>(h1b, csr, rowptr, deg, mB2, 2 * g);
        gemm_dual<<<dim3(782, 2, 1), 256, 0, stream>>>(mA2, mB2, 256, 256,
                                                       B2cat + (size_t)g * 131072,
                                                       hacc2, NN, 256, 512, 1.f / 7.f,
                                                       nullptr, 3);
    }
    ln_relu_b_k<<<25000, 256, 0, stream>>>(hacc2, ln_g + 256, ln_b + 256, h2b);

    // ---- classifier ----
    gemm_dual<<<dim3(782, 1, 1), 256, 0, stream>>>(h2b, h2b, 256, 256, Wc1T,
                                                   z1, NN, 128, 256, 1.f, bc1, 4);
    final_k<<<25000, 256, 0, stream>>>(z1, W2p, cp, out);
}